// Round 3
// baseline (424.784 us; speedup 1.0000x reference)
//
#include <hip/hip_runtime.h>
#include <math.h>

#define B_ 4
#define T_ 2048
#define C_ 768
#define DK_ 96
#define NA_ 8
#define M_ (B_*T_)      /* 8192 */
#define K2_ (2*C_)      /* 1536 */
#define NCH_ 128        /* EMA chunks per batch */
#define CK_ 16          /* EMA chunk len */

typedef __attribute__((ext_vector_type(8))) _Float16 half8;
typedef __attribute__((ext_vector_type(4))) _Float16 half4;
typedef __attribute__((ext_vector_type(4))) float floatx4;

#define AS1 __attribute__((address_space(1)))
#define AS3 __attribute__((address_space(3)))

__device__ __forceinline__ float sigm(float x){ return 1.f/(1.f + expf(-x)); }
__device__ __forceinline__ unsigned enc_max(float f){
  unsigned i = __float_as_uint(f);
  return (i & 0x80000000u) ? ~i : (i | 0x80000000u);
}
__device__ __forceinline__ float dec_max(unsigned u){
  unsigned i = (u & 0x80000000u) ? (u & 0x7FFFFFFFu) : ~u;
  return __uint_as_float(i);
}
__device__ __forceinline__ void gld16(const _Float16* g, _Float16* l){
  __builtin_amdgcn_global_load_lds((const AS1 unsigned int*)g, (AS3 unsigned int*)l, 16, 0, 0);
}

// ---------------- merged weight casts + cgE init ----------------
// blk ranges: [0,2304) wall quads; [2304,3840) wxfsc rows; [3840,4128) wqk rows / cgE
__global__ void k_cast_w(const float* __restrict__ Wp, const float* __restrict__ Wfast,
                         const float* __restrict__ Wslow, const float* __restrict__ Wsoma,
                         const float* __restrict__ Wxf, const float* __restrict__ Wcf,
                         const float* __restrict__ Wxs, const float* __restrict__ Wcs,
                         const float* __restrict__ Wq, const float* __restrict__ Wk,
                         _Float16* __restrict__ wall, _Float16* __restrict__ wxfsc,
                         _Float16* __restrict__ wqk, unsigned* __restrict__ cgE){
  int blk = blockIdx.x, tid = threadIdx.x;
  if (blk < 2304){
    int i = blk*256 + tid;                    // quad index over 4*C*C/4
    const int per = (C_*C_)/4;                // 147456
    int s = i / per, j = i - s*per;
    const float* src = s==0?Wp : s==1?Wfast : s==2?Wslow : Wsoma;
    float4 v = ((const float4*)src)[j];
    half4 h = { (_Float16)v.x, (_Float16)v.y, (_Float16)v.z, (_Float16)v.w };
    ((half4*)wall)[(size_t)s*per + j] = h;
  } else if (blk < 3840){
    int r = blk - 2304;                       // 0..1535
    const float* s0 = (r < C_) ? Wxf + (size_t)r*C_ : Wxs + (size_t)(r-C_)*C_;
    const float* s1 = (r < C_) ? Wcf + (size_t)r*C_ : Wcs + (size_t)(r-C_)*C_;
    if (tid < 192){
      float4 a = ((const float4*)s0)[tid];
      float4 b = ((const float4*)s1)[tid];
      half4 ha = { (_Float16)a.x,(_Float16)a.y,(_Float16)a.z,(_Float16)a.w };
      half4 hb = { (_Float16)b.x,(_Float16)b.y,(_Float16)b.z,(_Float16)b.w };
      ((half4*)(wxfsc + (size_t)r*K2_))[tid] = ha;
      ((half4*)(wxfsc + (size_t)r*K2_ + C_))[tid] = hb;
    }
  } else {
    int sub = blk - 3840;                     // 0..287
    if (sub >= 256){ cgE[(sub-256)*256 + tid] = 0u; return; }
    const float* src = (sub < 96) ? Wq + (size_t)sub*C_
                     : (sub < 192 ? Wk + (size_t)(sub-96)*C_ : nullptr);
    #pragma unroll
    for (int k = 0; k < 3; ++k){
      int c = tid + k*256;
      wqk[(size_t)sub*C_ + c] = src ? (_Float16)src[c] : (_Float16)0.f;
    }
  }
}

// ---------------- fused cast_x + gate-EMA pass1 ----------------
// grid B*NCH, block 192; thread owns 4 consecutive channels
__global__ __launch_bounds__(192) void k_castx_p1(
    const float* __restrict__ x, const float* __restrict__ tau,
    _Float16* __restrict__ xh, _Float16* __restrict__ xcat, float* __restrict__ Sg){
  float al = expf(-log1pf(expf(tau[0])));
  int blk = blockIdx.x, b = blk >> 7, ch = blk & (NCH_-1);
  int t0 = b*T_ + ch*CK_;
  int c4 = threadIdx.x;
  float s0=0.f,s1=0.f,s2=0.f,s3=0.f;
  for (int t = 0; t < CK_; ++t){
    float4 v = *(const float4*)(x + (size_t)(t0+t)*C_ + c4*4);
    half4 h = { (_Float16)v.x,(_Float16)v.y,(_Float16)v.z,(_Float16)v.w };
    *(half4*)(xh   + (size_t)(t0+t)*C_  + c4*4) = h;
    *(half4*)(xcat + (size_t)(t0+t)*K2_ + c4*4) = h;
    s0 = al*s0 + v.x; s1 = al*s1 + v.y; s2 = al*s2 + v.z; s3 = al*s3 + v.w;
  }
  float4 sv = { s0,s1,s2,s3 };
  *(float4*)(Sg + (size_t)blk*C_ + c4*4) = sv;
}

// ---------------- gate-EMA pass2+3 fused: per-block prefix re-scan + stream ----------------
__global__ __launch_bounds__(192) void k_gate_p23(
    const _Float16* __restrict__ xh, const float* __restrict__ Sg,
    const float* __restrict__ tau, _Float16* __restrict__ xcat){
  int blk = blockIdx.x, b = blk >> 7, ch = blk & (NCH_-1);
  float sp  = log1pf(expf(tau[0]));
  float al  = expf(-sp);
  float aCK = expf(-(float)CK_*sp);
  int c4 = threadIdx.x;
  float h0=0.f,h1=0.f,h2=0.f,h3=0.f;
  const float* Sb = Sg + ((size_t)b*NCH_)*C_ + c4*4;
  for (int j = 0; j < ch; ++j){
    float4 s = *(const float4*)(Sb + (size_t)j*C_);
    h0 = aCK*h0 + s.x; h1 = aCK*h1 + s.y; h2 = aCK*h2 + s.z; h3 = aCK*h3 + s.w;
  }
  int t0 = b*T_ + ch*CK_;
  for (int t = 0; t < CK_; ++t){
    half4 v = *(const half4*)(xh + (size_t)(t0+t)*C_ + c4*4);
    h0 = al*h0 + (float)v[0]; h1 = al*h1 + (float)v[1];
    h2 = al*h2 + (float)v[2]; h3 = al*h3 + (float)v[3];
    half4 o = { (_Float16)h0,(_Float16)h1,(_Float16)h2,(_Float16)h3 };
    *(half4*)(xcat + (size_t)(t0+t)*K2_ + C_ + c4*4) = o;
  }
}

// ---------------- fast/slow EMA pass1 (fused f+s) ----------------
__global__ __launch_bounds__(192) void k_fs_p1(
    const _Float16* __restrict__ xp, const _Float16* __restrict__ wgfs,
    const float* __restrict__ tf, const float* __restrict__ ts,
    float* __restrict__ Sf, float* __restrict__ Ss){
  float af = expf(-log1pf(expf(tf[0])));
  float as = expf(-log1pf(expf(ts[0])));
  int blk = blockIdx.x, b = blk >> 7, ch = blk & (NCH_-1);
  int t0 = b*T_ + ch*CK_;
  int c4 = threadIdx.x;
  float f0=0,f1=0,f2=0,f3=0, s0=0,s1=0,s2=0,s3=0;
  for (int t = 0; t < CK_; ++t){
    half4 p = *(const half4*)(xp + (size_t)(t0+t)*C_ + c4*4);
    half4 wf = *(const half4*)(wgfs + (size_t)(t0+t)*K2_ + c4*4);
    half4 ws = *(const half4*)(wgfs + (size_t)(t0+t)*K2_ + C_ + c4*4);
    f0 = af*f0 + (float)p[0]*(float)wf[0]; s0 = as*s0 + (float)p[0]*(float)ws[0];
    f1 = af*f1 + (float)p[1]*(float)wf[1]; s1 = as*s1 + (float)p[1]*(float)ws[1];
    f2 = af*f2 + (float)p[2]*(float)wf[2]; s2 = as*s2 + (float)p[2]*(float)ws[2];
    f3 = af*f3 + (float)p[3]*(float)wf[3]; s3 = as*s3 + (float)p[3]*(float)ws[3];
  }
  float4 fv = { f0,f1,f2,f3 }, sv = { s0,s1,s2,s3 };
  *(float4*)(Sf + (size_t)blk*C_ + c4*4) = fv;
  *(float4*)(Ss + (size_t)blk*C_ + c4*4) = sv;
}

// ---------------- fast/slow EMA pass2+3 fused: prefix re-scan + stream * cg + delta ----------------
__global__ __launch_bounds__(192) void k_fs_p23(
    const _Float16* __restrict__ xp, const _Float16* __restrict__ wgfs,
    const float* __restrict__ Sf, const float* __restrict__ Ss,
    const float* __restrict__ tf, const float* __restrict__ ts,
    const unsigned* __restrict__ cgE, const float* __restrict__ delta,
    _Float16* __restrict__ cf, _Float16* __restrict__ cs){
  int blk = blockIdx.x, b = blk >> 7, ch = blk & (NCH_-1);
  float spf = log1pf(expf(tf[0])), sps = log1pf(expf(ts[0]));
  float af = expf(-spf), as = expf(-sps);
  float afCK = expf(-(float)CK_*spf), asCK = expf(-(float)CK_*sps);
  int c4 = threadIdx.x;
  float f0=0,f1=0,f2=0,f3=0, s0=0,s1=0,s2=0,s3=0;
  const float* Sfb = Sf + ((size_t)b*NCH_)*C_ + c4*4;
  const float* Ssb = Ss + ((size_t)b*NCH_)*C_ + c4*4;
  for (int j = 0; j < ch; ++j){
    float4 a = *(const float4*)(Sfb + (size_t)j*C_);
    float4 c = *(const float4*)(Ssb + (size_t)j*C_);
    f0 = afCK*f0 + a.x; f1 = afCK*f1 + a.y; f2 = afCK*f2 + a.z; f3 = afCK*f3 + a.w;
    s0 = asCK*s0 + c.x; s1 = asCK*s1 + c.y; s2 = asCK*s2 + c.z; s3 = asCK*s3 + c.w;
  }
  float4 d = *(const float4*)(delta + (size_t)b*C_ + c4*4);
  int t0 = b*T_ + ch*CK_;
  const unsigned* cgp = cgE + t0;
  for (int t = 0; t < CK_; ++t){
    float cgv = sigm(dec_max(cgp[t]));
    half4 p = *(const half4*)(xp + (size_t)(t0+t)*C_ + c4*4);
    half4 wf = *(const half4*)(wgfs + (size_t)(t0+t)*K2_ + c4*4);
    half4 ws = *(const half4*)(wgfs + (size_t)(t0+t)*K2_ + C_ + c4*4);
    f0 = af*f0 + (float)p[0]*(float)wf[0]; s0 = as*s0 + (float)p[0]*(float)ws[0];
    f1 = af*f1 + (float)p[1]*(float)wf[1]; s1 = as*s1 + (float)p[1]*(float)ws[1];
    f2 = af*f2 + (float)p[2]*(float)wf[2]; s2 = as*s2 + (float)p[2]*(float)ws[2];
    f3 = af*f3 + (float)p[3]*(float)wf[3]; s3 = as*s3 + (float)p[3]*(float)ws[3];
    half4 of = { (_Float16)(f0*cgv + d.x), (_Float16)(f1*cgv + d.y),
                 (_Float16)(f2*cgv + d.z), (_Float16)(f3*cgv + d.w) };
    half4 os = { (_Float16)(s0*cgv + d.x), (_Float16)(s1*cgv + d.y),
                 (_Float16)(s2*cgv + d.z), (_Float16)(s3*cgv + d.w) };
    *(half4*)(cf + (size_t)(t0+t)*C_ + c4*4) = of;
    *(half4*)(cs + (size_t)(t0+t)*C_ + c4*4) = os;
  }
}

// ---------------- GEMM tile core (128x128, BK=64, async LDS + XOR swizzle) ----------------
template<int K>
__device__ __forceinline__ void gemm_tile(const _Float16* __restrict__ A, const _Float16* __restrict__ W,
                                          int m0, int n0, _Float16* As, _Float16* Ws,
                                          floatx4 acc[4][4]){
  int tid = threadIdx.x;
  int wave = tid >> 6, lane = tid & 63;
  int wr = wave >> 1, wc = wave & 1;
  int lr = lane & 15, lq = lane >> 4;
  for (int k0 = 0; k0 < K; k0 += 64){
    #pragma unroll
    for (int it = 0; it < 4; ++it){
      int cb = it*256 + wave*64;          // wave-uniform chunk base
      int ck = cb + lane;                 // this lane's chunk
      int row = ck >> 3;
      int kp = (ck & 7) ^ (row & 7);      // XOR swizzle
      gld16(A + (size_t)(m0+row)*K + k0 + kp*8, As + (size_t)cb*8);
      gld16(W + (size_t)(n0+row)*K + k0 + kp*8, Ws + (size_t)cb*8);
    }
    asm volatile("s_waitcnt vmcnt(0)" ::: "memory");
    __syncthreads();
    #pragma unroll
    for (int ks = 0; ks < 2; ++ks){
      half8 fa[4], fb[4];
      int off = (((ks*4 + lq) ^ (lr & 7)) << 3);
      #pragma unroll
      for (int i = 0; i < 4; ++i){
        fa[i] = *(const half8*)(As + (wr*64 + i*16 + lr)*64 + off);
        fb[i] = *(const half8*)(Ws + (wc*64 + i*16 + lr)*64 + off);
      }
      #pragma unroll
      for (int i = 0; i < 4; ++i)
        #pragma unroll
        for (int j = 0; j < 4; ++j)
          acc[i][j] = __builtin_amdgcn_mfma_f32_16x16x32_f16(fa[i], fb[j], acc[i][j], 0, 0, 0);
    }
    __syncthreads();
  }
}

__device__ __forceinline__ void store_tile_f16(floatx4 acc[4][4], _Float16* __restrict__ out, int ldo,
                                               const float* bias, const float* bias2,
                                               int m0, int n0, int act){
  int tid = threadIdx.x;
  int wave = tid >> 6, lane = tid & 63;
  int wr = wave >> 1, wc = wave & 1;
  int lr = lane & 15, lq = lane >> 4;
  #pragma unroll
  for (int i = 0; i < 4; ++i){
    #pragma unroll
    for (int j = 0; j < 4; ++j){
      int col = n0 + wc*64 + j*16 + lr;
      float bv = 0.f;
      if (bias) bv = (bias2 && col >= C_) ? bias2[col - C_] : bias[col];
      #pragma unroll
      for (int r = 0; r < 4; ++r){
        int rowm = m0 + wr*64 + i*16 + lq*4 + r;
        float z = acc[i][j][r] + bv;
        if (act == 1) z = tanhf(z);
        else if (act == 2) z = sigm(z);
        out[(size_t)rowm*ldo + col] = (_Float16)z;
      }
    }
  }
}

// stage 3: xp (tanh), wg_f||wg_s (sigmoid, K=1536), q||k (none, padded N=256)
__global__ __launch_bounds__(256,4) void k_gemm_s3(
    const _Float16* __restrict__ xh, const _Float16* __restrict__ xcat,
    const _Float16* __restrict__ wph, const _Float16* __restrict__ wxfsc,
    const _Float16* __restrict__ wqk,
    const float* __restrict__ bp, const float* __restrict__ bxf, const float* __restrict__ bxs,
    _Float16* __restrict__ xph, _Float16* __restrict__ wgfs, _Float16* __restrict__ qk)
{
  __shared__ _Float16 As[128*64];
  __shared__ _Float16 Ws[128*64];
  floatx4 acc[4][4] = {};
  int m0 = blockIdx.x * 128;
  int ny = blockIdx.y;
  if (ny < 6){
    gemm_tile<C_>(xh, wph, m0, ny*128, As, Ws, acc);
    store_tile_f16(acc, xph, C_, bp, nullptr, m0, ny*128, 1);
  } else if (ny < 18){
    int n0 = (ny-6)*128;
    gemm_tile<K2_>(xcat, wxfsc, m0, n0, As, Ws, acc);
    store_tile_f16(acc, wgfs, K2_, bxf, bxs, m0, n0, 2);
  } else {
    int n0 = (ny-18)*128;
    gemm_tile<C_>(xh, wqk, m0, n0, As, Ws, acc);
    store_tile_f16(acc, qk, 256, nullptr, nullptr, m0, n0, 0);
  }
}

// stage 7: gf (sigmoid), gs (sigmoid), soma (tanh) -> f16 buffers
__global__ __launch_bounds__(256,4) void k_gemm_s7(
    const _Float16* __restrict__ cf, const _Float16* __restrict__ cs, const _Float16* __restrict__ xh,
    const _Float16* __restrict__ wfh, const _Float16* __restrict__ wsh, const _Float16* __restrict__ wsomah,
    const float* __restrict__ bf, const float* __restrict__ bs, const float* __restrict__ bso,
    _Float16* __restrict__ gfb, _Float16* __restrict__ gsb, _Float16* __restrict__ somab)
{
  __shared__ _Float16 As[128*64];
  __shared__ _Float16 Ws[128*64];
  floatx4 acc[4][4] = {};
  int m0 = blockIdx.x * 128;
  int s = blockIdx.y / 6, nt = (blockIdx.y % 6) * 128;
  const _Float16* A = (s==0) ? cf : (s==1) ? cs : xh;
  const _Float16* W = (s==0) ? wfh : (s==1) ? wsh : wsomah;
  const float* bias = (s==0) ? bf : (s==1) ? bs : bso;
  _Float16* out = (s==0) ? gfb : (s==1) ? gsb : somab;
  gemm_tile<C_>(A, W, m0, nt, As, Ws, acc);
  store_tile_f16(acc, out, C_, bias, nullptr, m0, nt, (s==2) ? 1 : 2);
}

// ---------------- causal max-score (MFMA); qk row stride 256 (q at 0, k at 96) ----------------
#define SLDK 104
__global__ __launch_bounds__(256,3) void k_score(
    const _Float16* __restrict__ qk, unsigned* __restrict__ cgE)
{
  __shared__ _Float16 Qs[128*SLDK];
  __shared__ _Float16 Ks[128*SLDK];
  int b = blockIdx.y;
  int p = blockIdx.x;
  int ti = (int)((sqrtf(8.f*p + 1.f) - 1.f)*0.5f);
  while ((ti+1)*(ti+2)/2 <= p) ++ti;
  while (ti*(ti+1)/2 > p) --ti;
  int sj = p - ti*(ti+1)/2;

  int tid = threadIdx.x;
  const _Float16* qg = qk + (size_t)(b*T_ + ti*128)*256;
  const _Float16* kg = qk + (size_t)(b*T_ + sj*128)*256 + 96;
  #pragma unroll
  for (int r = 0; r < 6; ++r){
    int ci = tid + r*256;
    int row = ci / 12, kp = ci % 12;
    *(uint4*)(&Qs[row*SLDK + kp*8]) = *(const uint4*)(qg + (size_t)row*256 + kp*8);
    *(uint4*)(&Ks[row*SLDK + kp*8]) = *(const uint4*)(kg + (size_t)row*256 + kp*8);
  }
  __syncthreads();

  int wave = tid >> 6, lane = tid & 63;
  int wr = wave >> 1, wc = wave & 1;
  int lr = lane & 15, lq = lane >> 4;
  floatx4 acc[4][4] = {};
  #pragma unroll
  for (int ks = 0; ks < 3; ++ks){
    half8 fa[4], fb[4];
    #pragma unroll
    for (int i = 0; i < 4; ++i){
      fa[i] = *(const half8*)(&Qs[(wr*64 + i*16 + lr)*SLDK + ks*32 + lq*8]);
      fb[i] = *(const half8*)(&Ks[(wc*64 + i*16 + lr)*SLDK + ks*32 + lq*8]);
    }
    #pragma unroll
    for (int i = 0; i < 4; ++i)
      #pragma unroll
      for (int j = 0; j < 4; ++j)
        acc[i][j] = __builtin_amdgcn_mfma_f32_16x16x32_f16(fa[i], fb[j], acc[i][j], 0, 0, 0);
  }
  const float scale = 0.10206207f;   // 96^-0.5
  #pragma unroll
  for (int i = 0; i < 4; ++i){
    #pragma unroll
    for (int r = 0; r < 4; ++r){
      int tg = ti*128 + wr*64 + i*16 + lq*4 + r;
      float v = -3.0e38f;
      #pragma unroll
      for (int j = 0; j < 4; ++j){
        int sg = sj*128 + wc*64 + j*16 + lr;
        if (sg <= tg) v = fmaxf(v, acc[i][j][r]*scale);
      }
      #pragma unroll
      for (int off = 1; off < 16; off <<= 1) v = fmaxf(v, __shfl_xor(v, off, 16));
      if (lr == 0) atomicMax(&cgE[(size_t)b*T_ + tg], enc_max(v));
    }
  }
}

// ---------------- anchors ----------------
__global__ __launch_bounds__(256) void k_anchor(const float* __restrict__ x, const float* __restrict__ Wanc,
                        const float* __restrict__ banc, const float* __restrict__ scales,
                        float* __restrict__ delta){
  __shared__ float xs[NA_*C_];
  __shared__ float part[NA_*128];
  int b = blockIdx.y, ct = blockIdx.x;
  int tid = threadIdx.x;
  for (int i = tid; i < NA_*C_; i += 256){
    int n = i / C_, c = i - n*C_;
    xs[i] = x[(size_t)(b*T_ + n*(T_/NA_))*C_ + c];
  }
  __syncthreads();
  int col = ct*128 + (tid & 127), kh = tid >> 7;
  float acc[NA_] = {0,0,0,0,0,0,0,0};
  const float* wrow = Wanc + (size_t)col*C_ + kh*384;
  const float* xk = xs + kh*384;
  for (int k = 0; k < 384; ++k){
    float wv = wrow[k];
    #pragma unroll
    for (int n = 0; n < NA_; ++n) acc[n] += xk[n*C_ + k]*wv;
  }
  if (kh){
    #pragma unroll
    for (int n = 0; n < NA_; ++n) part[n*128 + (tid & 127)] = acc[n];
  }
  __syncthreads();
  if (!kh){
    float d = 0.f;
    float bv = banc[col];
    #pragma unroll
    for (int n = 0; n < NA_; ++n){
      float a = tanhf(acc[n] + part[n*128 + (tid & 127)] + bv);
      d += sigm(scales[n]) * a;
    }
    delta[(size_t)b*C_ + col] = d;
  }
}

// ---------------- fused blend + soma-mul + LayerNorm (192 thr, half4) ----------------
__global__ __launch_bounds__(192) void k_ln(const _Float16* __restrict__ gfb,
                                            const _Float16* __restrict__ gsb,
                                            const _Float16* __restrict__ somab,
                                            const float* __restrict__ blendr,
                                            const float* __restrict__ g, const float* __restrict__ be,
                                            float* __restrict__ out){
  int row = blockIdx.x;
  int tid = threadIdx.x;
  float bl = sigm(blendr[0]);
  size_t base = (size_t)row*C_ + tid*4;
  half4 gf4 = *(const half4*)(gfb + base);
  half4 gs4 = *(const half4*)(gsb + base);
  half4 so4 = *(const half4*)(somab + base);
  float v[4];
  #pragma unroll
  for (int i = 0; i < 4; ++i){
    float gf = (float)gf4[i], gs = (float)gs4[i], so = (float)so4[i];
    v[i] = so * (gf + bl*(gs - gf));
  }
  float s = v[0]+v[1]+v[2]+v[3];
  float ss = v[0]*v[0]+v[1]*v[1]+v[2]*v[2]+v[3]*v[3];
  #pragma unroll
  for (int off = 1; off < 64; off <<= 1){ s += __shfl_xor(s, off); ss += __shfl_xor(ss, off); }
  __shared__ float sb[6];
  int wave = tid >> 6, lane = tid & 63;
  if (lane == 0){ sb[wave] = s; sb[3+wave] = ss; }
  __syncthreads();
  s  = sb[0]+sb[1]+sb[2];
  ss = sb[3]+sb[4]+sb[5];
  float mu  = s * (1.f/C_);
  float var = ss * (1.f/C_) - mu*mu;
  float inv = rsqrtf(var + 1e-5f);
  float4 o;
  o.x = (v[0]-mu)*inv*g[tid*4+0] + be[tid*4+0];
  o.y = (v[1]-mu)*inv*g[tid*4+1] + be[tid*4+1];
  o.z = (v[2]-mu)*inv*g[tid*4+2] + be[tid*4+2];
  o.w = (v[3]-mu)*inv*g[tid*4+3] + be[tid*4+3];
  *(float4*)(out + base) = o;
}

// ---------------- launch ----------------
extern "C" void kernel_launch(void* const* d_in, const int* in_sizes, int n_in,
                              void* d_out, int out_size, void* d_ws, size_t ws_size,
                              hipStream_t stream){
  (void)in_sizes; (void)n_in; (void)out_size;
  const float* x        = (const float*)d_in[0];
  const float* tau_gate = (const float*)d_in[1];
  const float* tau_fast = (const float*)d_in[2];
  const float* tau_slow = (const float*)d_in[3];
  const float* Wp   = (const float*)d_in[4];  const float* bp    = (const float*)d_in[5];
  const float* Wxf  = (const float*)d_in[6];  const float* bxf   = (const float*)d_in[7];
  const float* Wxs  = (const float*)d_in[8];  const float* bxs   = (const float*)d_in[9];
  const float* Wcf  = (const float*)d_in[10]; const float* Wcs   = (const float*)d_in[11];
  const float* Wq   = (const float*)d_in[12]; const float* Wk    = (const float*)d_in[13];
  const float* Wfast= (const float*)d_in[14]; const float* bfast = (const float*)d_in[15];
  const float* Wslow= (const float*)d_in[16]; const float* bslow = (const float*)d_in[17];
  const float* Wsoma= (const float*)d_in[18]; const float* bsoma = (const float*)d_in[19];
  const float* Wanc = (const float*)d_in[20]; const float* banc  = (const float*)d_in[21];
  const float* ascl = (const float*)d_in[22]; const float* blendr= (const float*)d_in[23];
  const float* lng  = (const float*)d_in[24]; const float* lnb   = (const float*)d_in[25];
  float* out = (float*)d_out;

  char* w = (char*)d_ws;
  auto alloc = [&](size_t bytes)->void*{
    void* p = (void*)w; w += (bytes + 255) & ~(size_t)255; return p;
  };
  _Float16* xh    = (_Float16*)alloc((size_t)M_*C_*2);
  _Float16* xcat  = (_Float16*)alloc((size_t)M_*K2_*2);
  _Float16* wall  = (_Float16*)alloc((size_t)4*C_*C_*2);
  _Float16* wxfsc = (_Float16*)alloc((size_t)K2_*K2_*2);
  _Float16* wqk   = (_Float16*)alloc((size_t)256*C_*2);
  _Float16* xph   = (_Float16*)alloc((size_t)M_*C_*2);
  _Float16* wgfs  = (_Float16*)alloc((size_t)M_*K2_*2);
  _Float16* qk    = (_Float16*)alloc((size_t)M_*256*2);
  unsigned* cgE   = (unsigned*)alloc((size_t)M_*4);
  float* Sg = (float*)alloc((size_t)B_*NCH_*C_*4);
  float* Sf = (float*)alloc((size_t)B_*NCH_*C_*4);
  float* Ss = (float*)alloc((size_t)B_*NCH_*C_*4);
  float* dlt = (float*)alloc((size_t)B_*C_*4);
  // reuse regions (stream-ordered, producer consumed before overwrite):
  _Float16* cfh   = xcat;                      // cf/cs overwrite xcat after stage-3 GEMM
  _Float16* csh   = xcat + (size_t)M_*C_;
  _Float16* gfb   = wgfs;                      // gf/gs overwrite wgfs after fs_p23
  _Float16* gsb   = wgfs + (size_t)M_*C_;
  _Float16* somab = xph;                       // soma overwrites xph (consumed by fs chain)
  if ((size_t)(w - (char*)d_ws) > ws_size) return;

  const _Float16* wph    = wall;
  const _Float16* wfh    = wall + (size_t)C_*C_;
  const _Float16* wsh    = wall + (size_t)2*C_*C_;
  const _Float16* wsomah = wall + (size_t)3*C_*C_;

  // 1) all weight casts + cgE init (one launch)
  k_cast_w<<<4128, 256, 0, stream>>>(Wp, Wfast, Wslow, Wsoma, Wxf, Wcf, Wxs, Wcs, Wq, Wk,
                                     wall, wxfsc, wqk, cgE);
  // 2) cast x -> xh + xcat[:, :C] + gate chunk sums
  k_castx_p1<<<B_*NCH_, 192, 0, stream>>>(x, tau_gate, xh, xcat, Sg);
  // 3) gate EMA prefix+stream -> xcat[:, C:]
  k_gate_p23<<<B_*NCH_, 192, 0, stream>>>(xh, Sg, tau_gate, xcat);
  // 4) stage 3: xp + wg_f||wg_s + q||k in one launch
  k_gemm_s3<<<dim3(M_/128, 20), 256, 0, stream>>>(xh, xcat, wph, wxfsc, wqk,
                                                  bp, bxf, bxs, xph, wgfs, qk);
  // 5) causal max score
  k_score<<<dim3(136, B_), 256, 0, stream>>>(qk, cgE);
  // 6) anchors
  k_anchor<<<dim3(C_/128, B_), 256, 0, stream>>>(x, Wanc, banc, ascl, dlt);
  // 7) fast/slow EMA pass1
  k_fs_p1<<<B_*NCH_, 192, 0, stream>>>(xph, wgfs, tau_fast, tau_slow, Sf, Ss);
  // 8) fast/slow EMA prefix+stream (* cg + delta) -> cf/cs
  k_fs_p23<<<B_*NCH_, 192, 0, stream>>>(xph, wgfs, Sf, Ss, tau_fast, tau_slow,
                                        cgE, dlt, cfh, csh);
  // 9) stage 7: gf + gs + soma in one launch
  k_gemm_s7<<<dim3(M_/128, 18), 256, 0, stream>>>(cfh, csh, xh, wfh, wsh, wsomah,
                                                  bfast, bslow, bsoma, gfb, gsb, somab);
  // 10) fused blend + mul + LN
  k_ln<<<M_, 192, 0, stream>>>(gfb, gsb, somab, blendr, lng, lnb, out);
}

// Round 4
// 413.680 us; speedup vs baseline: 1.0268x; 1.0268x over previous
//
#include <hip/hip_runtime.h>
#include <math.h>

#define B_ 4
#define T_ 2048
#define C_ 768
#define DK_ 96
#define NA_ 8
#define M_ (B_*T_)      /* 8192 */
#define K2_ (2*C_)      /* 1536 */
#define NCH_ 256        /* EMA chunks per batch */
#define CK_ 8           /* EMA chunk len */

typedef __attribute__((ext_vector_type(8))) _Float16 half8;
typedef __attribute__((ext_vector_type(4))) _Float16 half4;
typedef __attribute__((ext_vector_type(4))) float floatx4;

#define AS1 __attribute__((address_space(1)))
#define AS3 __attribute__((address_space(3)))

__device__ __forceinline__ float sigm(float x){ return 1.f/(1.f + expf(-x)); }
__device__ __forceinline__ unsigned enc_max(float f){
  unsigned i = __float_as_uint(f);
  return (i & 0x80000000u) ? ~i : (i | 0x80000000u);
}
__device__ __forceinline__ float dec_max(unsigned u){
  unsigned i = (u & 0x80000000u) ? (u & 0x7FFFFFFFu) : ~u;
  return __uint_as_float(i);
}
__device__ __forceinline__ void gld16(const _Float16* g, _Float16* l){
  __builtin_amdgcn_global_load_lds((const AS1 unsigned int*)g, (AS3 unsigned int*)l, 16, 0, 0);
}

// ---------------- merged weight casts + cgE init ----------------
// wall layout (8 C*C f16 mats): Wp, Wfast, Wslow, Wsoma, Wxf, Wxs, Wcf, Wcs
// blk [0,4608): wall quads; [4608,4896): wqk rows / cgE zero
__global__ void k_cast_w8(const float* __restrict__ Wp, const float* __restrict__ Wfast,
                          const float* __restrict__ Wslow, const float* __restrict__ Wsoma,
                          const float* __restrict__ Wxf, const float* __restrict__ Wxs,
                          const float* __restrict__ Wcf, const float* __restrict__ Wcs,
                          const float* __restrict__ Wq, const float* __restrict__ Wk,
                          _Float16* __restrict__ wall, _Float16* __restrict__ wqk,
                          unsigned* __restrict__ cgE){
  int blk = blockIdx.x, tid = threadIdx.x;
  if (blk < 4608){
    int i = blk*256 + tid;                    // quad index over 8*C*C/4
    const int per = (C_*C_)/4;                // 147456
    int s = i / per, j = i - s*per;
    const float* src = s==0?Wp : s==1?Wfast : s==2?Wslow : s==3?Wsoma
                     : s==4?Wxf : s==5?Wxs : s==6?Wcf : Wcs;
    float4 v = ((const float4*)src)[j];
    half4 h = { (_Float16)v.x, (_Float16)v.y, (_Float16)v.z, (_Float16)v.w };
    ((half4*)wall)[(size_t)s*per + j] = h;
  } else {
    int sub = blk - 4608;                     // 0..287
    if (sub >= 256){ cgE[(sub-256)*256 + tid] = 0u; return; }
    const float* src = (sub < 96) ? Wq + (size_t)sub*C_
                     : (sub < 192 ? Wk + (size_t)(sub-96)*C_ : nullptr);
    #pragma unroll
    for (int k = 0; k < 3; ++k){
      int c = tid + k*256;
      wqk[(size_t)sub*C_ + c] = src ? (_Float16)src[c] : (_Float16)0.f;
    }
  }
}

// ---------------- fused cast_x + gate-EMA pass1 (CK=8 fully unrolled) ----------------
__global__ __launch_bounds__(192) void k_castx_p1(
    const float* __restrict__ x, const float* __restrict__ tau,
    _Float16* __restrict__ xh, float* __restrict__ Sg){
  float al = expf(-log1pf(expf(tau[0])));
  int blk = blockIdx.x, b = blk >> 8, ch = blk & (NCH_-1);
  int t0 = b*T_ + ch*CK_;
  int c4 = threadIdx.x;
  float s0=0.f,s1=0.f,s2=0.f,s3=0.f;
  #pragma unroll
  for (int t = 0; t < CK_; ++t){
    float4 v = *(const float4*)(x + (size_t)(t0+t)*C_ + c4*4);
    half4 h = { (_Float16)v.x,(_Float16)v.y,(_Float16)v.z,(_Float16)v.w };
    *(half4*)(xh + (size_t)(t0+t)*C_ + c4*4) = h;
    s0 = al*s0 + v.x; s1 = al*s1 + v.y; s2 = al*s2 + v.z; s3 = al*s3 + v.w;
  }
  float4 sv = { s0,s1,s2,s3 };
  *(float4*)(Sg + (size_t)blk*C_ + c4*4) = sv;
}

// ---------------- chunk-prefix scans (exclusive) ----------------
// gate: grid B*3 blocks x 256 thr, one channel per thread
__global__ __launch_bounds__(256) void k_p2_gate(const float* __restrict__ S, float* __restrict__ H,
                                                 const float* __restrict__ tau){
  int blk = blockIdx.x;
  int b = blk / 3, c = (blk - b*3)*256 + threadIdx.x;
  float aCK = expf(-(float)CK_ * log1pf(expf(tau[0])));
  float h = 0.f;
  for (int ch = 0; ch < NCH_; ++ch){
    size_t idx = (size_t)(b*NCH_ + ch)*C_ + c;
    H[idx] = h;
    h = aCK*h + S[idx];
  }
}

// fast+slow: grid 2*B*3 blocks
__global__ __launch_bounds__(256) void k_p2_fs(const float* __restrict__ Sf, const float* __restrict__ Ss,
                                               float* __restrict__ Hf, float* __restrict__ Hs,
                                               const float* __restrict__ tf, const float* __restrict__ ts){
  int blk = blockIdx.x;
  int which = blk / 12, sub = blk - which*12;
  int b = sub / 3, c = (sub - b*3)*256 + threadIdx.x;
  const float* S = which ? Ss : Sf;
  float* H = which ? Hs : Hf;
  float aCK = expf(-(float)CK_ * log1pf(expf(which ? ts[0] : tf[0])));
  float h = 0.f;
  for (int ch = 0; ch < NCH_; ++ch){
    size_t idx = (size_t)(b*NCH_ + ch)*C_ + c;
    H[idx] = h;
    h = aCK*h + S[idx];
  }
}

// ---------------- gate-EMA pass3: stream -> gate buffer (f16, stride C) ----------------
__global__ __launch_bounds__(192) void k_gate_p3(
    const _Float16* __restrict__ xh, const float* __restrict__ H,
    const float* __restrict__ tau, _Float16* __restrict__ gate){
  float al = expf(-log1pf(expf(tau[0])));
  int blk = blockIdx.x, b = blk >> 8, ch = blk & (NCH_-1);
  int c4 = threadIdx.x;
  float4 h0 = *(const float4*)(H + (size_t)blk*C_ + c4*4);
  float g0=h0.x, g1=h0.y, g2=h0.z, g3=h0.w;
  int t0 = b*T_ + ch*CK_;
  #pragma unroll
  for (int t = 0; t < CK_; ++t){
    half4 v = *(const half4*)(xh + (size_t)(t0+t)*C_ + c4*4);
    g0 = al*g0 + (float)v[0]; g1 = al*g1 + (float)v[1];
    g2 = al*g2 + (float)v[2]; g3 = al*g3 + (float)v[3];
    half4 o = { (_Float16)g0,(_Float16)g1,(_Float16)g2,(_Float16)g3 };
    *(half4*)(gate + (size_t)(t0+t)*C_ + c4*4) = o;
  }
}

// ---------------- fast/slow EMA pass1 ----------------
__global__ __launch_bounds__(192) void k_fs_p1(
    const _Float16* __restrict__ xp, const _Float16* __restrict__ wgfs,
    const float* __restrict__ tf, const float* __restrict__ ts,
    float* __restrict__ Sf, float* __restrict__ Ss){
  float af = expf(-log1pf(expf(tf[0])));
  float as = expf(-log1pf(expf(ts[0])));
  int blk = blockIdx.x, b = blk >> 8, ch = blk & (NCH_-1);
  int t0 = b*T_ + ch*CK_;
  int c4 = threadIdx.x;
  float f0=0,f1=0,f2=0,f3=0, s0=0,s1=0,s2=0,s3=0;
  #pragma unroll
  for (int t = 0; t < CK_; ++t){
    half4 p = *(const half4*)(xp + (size_t)(t0+t)*C_ + c4*4);
    half4 wf = *(const half4*)(wgfs + (size_t)(t0+t)*K2_ + c4*4);
    half4 ws = *(const half4*)(wgfs + (size_t)(t0+t)*K2_ + C_ + c4*4);
    f0 = af*f0 + (float)p[0]*(float)wf[0]; s0 = as*s0 + (float)p[0]*(float)ws[0];
    f1 = af*f1 + (float)p[1]*(float)wf[1]; s1 = as*s1 + (float)p[1]*(float)ws[1];
    f2 = af*f2 + (float)p[2]*(float)wf[2]; s2 = as*s2 + (float)p[2]*(float)ws[2];
    f3 = af*f3 + (float)p[3]*(float)wf[3]; s3 = as*s3 + (float)p[3]*(float)ws[3];
  }
  float4 fv = { f0,f1,f2,f3 }, sv = { s0,s1,s2,s3 };
  *(float4*)(Sf + (size_t)blk*C_ + c4*4) = fv;
  *(float4*)(Ss + (size_t)blk*C_ + c4*4) = sv;
}

// ---------------- fast/slow EMA pass3: stream * cg + delta -> cf/cs ----------------
__global__ __launch_bounds__(192) void k_fs_p3(
    const _Float16* __restrict__ xp, const _Float16* __restrict__ wgfs,
    const float* __restrict__ Hf, const float* __restrict__ Hs,
    const float* __restrict__ tf, const float* __restrict__ ts,
    const unsigned* __restrict__ cgE, const float* __restrict__ delta,
    _Float16* __restrict__ cf, _Float16* __restrict__ cs){
  float af = expf(-log1pf(expf(tf[0])));
  float as = expf(-log1pf(expf(ts[0])));
  int blk = blockIdx.x, b = blk >> 8, ch = blk & (NCH_-1);
  int c4 = threadIdx.x;
  float4 hf = *(const float4*)(Hf + (size_t)blk*C_ + c4*4);
  float4 hs = *(const float4*)(Hs + (size_t)blk*C_ + c4*4);
  float f0=hf.x,f1=hf.y,f2=hf.z,f3=hf.w;
  float s0=hs.x,s1=hs.y,s2=hs.z,s3=hs.w;
  float4 d = *(const float4*)(delta + (size_t)b*C_ + c4*4);
  int t0 = b*T_ + ch*CK_;
  const unsigned* cgp = cgE + t0;
  #pragma unroll
  for (int t = 0; t < CK_; ++t){
    float cgv = sigm(dec_max(cgp[t]));
    half4 p = *(const half4*)(xp + (size_t)(t0+t)*C_ + c4*4);
    half4 wf = *(const half4*)(wgfs + (size_t)(t0+t)*K2_ + c4*4);
    half4 ws = *(const half4*)(wgfs + (size_t)(t0+t)*K2_ + C_ + c4*4);
    f0 = af*f0 + (float)p[0]*(float)wf[0]; s0 = as*s0 + (float)p[0]*(float)ws[0];
    f1 = af*f1 + (float)p[1]*(float)wf[1]; s1 = as*s1 + (float)p[1]*(float)ws[1];
    f2 = af*f2 + (float)p[2]*(float)wf[2]; s2 = as*s2 + (float)p[2]*(float)ws[2];
    f3 = af*f3 + (float)p[3]*(float)wf[3]; s3 = as*s3 + (float)p[3]*(float)ws[3];
    half4 of = { (_Float16)(f0*cgv + d.x), (_Float16)(f1*cgv + d.y),
                 (_Float16)(f2*cgv + d.z), (_Float16)(f3*cgv + d.w) };
    half4 os = { (_Float16)(s0*cgv + d.x), (_Float16)(s1*cgv + d.y),
                 (_Float16)(s2*cgv + d.z), (_Float16)(s3*cgv + d.w) };
    *(half4*)(cf + (size_t)(t0+t)*C_ + c4*4) = of;
    *(half4*)(cs + (size_t)(t0+t)*C_ + c4*4) = os;
  }
}

// ---------------- GEMM tile core (128x128, K=768, BK=64, async LDS + XOR swizzle) ----------------
__device__ __forceinline__ void gemm_tile(const _Float16* __restrict__ A, const _Float16* __restrict__ W,
                                          int m0, int n0, _Float16* As, _Float16* Ws,
                                          floatx4 acc[4][4]){
  int tid = threadIdx.x;
  int wave = tid >> 6, lane = tid & 63;
  int wr = wave >> 1, wc = wave & 1;
  int lr = lane & 15, lq = lane >> 4;
  for (int k0 = 0; k0 < C_; k0 += 64){
    #pragma unroll
    for (int it = 0; it < 4; ++it){
      int cb = it*256 + wave*64;          // wave-uniform chunk base
      int ck = cb + lane;                 // this lane's chunk
      int row = ck >> 3;
      int kp = (ck & 7) ^ (row & 7);      // XOR swizzle
      gld16(A + (size_t)(m0+row)*C_ + k0 + kp*8, As + (size_t)cb*8);
      gld16(W + (size_t)(n0+row)*C_ + k0 + kp*8, Ws + (size_t)cb*8);
    }
    asm volatile("s_waitcnt vmcnt(0)" ::: "memory");
    __syncthreads();
    #pragma unroll
    for (int ks = 0; ks < 2; ++ks){
      half8 fa[4], fb[4];
      int off = (((ks*4 + lq) ^ (lr & 7)) << 3);
      #pragma unroll
      for (int i = 0; i < 4; ++i){
        fa[i] = *(const half8*)(As + (wr*64 + i*16 + lr)*64 + off);
        fb[i] = *(const half8*)(Ws + (wc*64 + i*16 + lr)*64 + off);
      }
      #pragma unroll
      for (int i = 0; i < 4; ++i)
        #pragma unroll
        for (int j = 0; j < 4; ++j)
          acc[i][j] = __builtin_amdgcn_mfma_f32_16x16x32_f16(fa[i], fb[j], acc[i][j], 0, 0, 0);
    }
    __syncthreads();
  }
}

__device__ __forceinline__ void store_tile_f16(floatx4 acc[4][4], _Float16* __restrict__ out, int ldo,
                                               const float* bias, const float* bias2,
                                               int m0, int n0, int act){
  int tid = threadIdx.x;
  int wave = tid >> 6, lane = tid & 63;
  int wr = wave >> 1, wc = wave & 1;
  int lr = lane & 15, lq = lane >> 4;
  #pragma unroll
  for (int i = 0; i < 4; ++i){
    #pragma unroll
    for (int j = 0; j < 4; ++j){
      int col = n0 + wc*64 + j*16 + lr;
      float bv = 0.f;
      if (bias) bv = (bias2 && col >= C_) ? bias2[col - C_] : bias[col];
      #pragma unroll
      for (int r = 0; r < 4; ++r){
        int rowm = m0 + wr*64 + i*16 + lq*4 + r;
        float z = acc[i][j][r] + bv;
        if (act == 1) z = tanhf(z);
        else if (act == 2) z = sigm(z);
        out[(size_t)rowm*ldo + col] = (_Float16)z;
      }
    }
  }
}

// stage 3: xp (tanh); wg = xh@[Wxf;Wxs] + gate@[Wcf;Wcs] (sigmoid, split-K); q||k
__global__ __launch_bounds__(256,4) void k_gemm_s3(
    const _Float16* __restrict__ xh, const _Float16* __restrict__ gate,
    const _Float16* __restrict__ wall, const _Float16* __restrict__ wqk,
    const float* __restrict__ bp, const float* __restrict__ bxf, const float* __restrict__ bxs,
    _Float16* __restrict__ xph, _Float16* __restrict__ wgfs, _Float16* __restrict__ qk)
{
  __shared__ _Float16 As[128*64];
  __shared__ _Float16 Ws[128*64];
  const size_t per = (size_t)C_*C_;
  const _Float16* wph  = wall;            // Wp
  const _Float16* wxfs = wall + 4*per;    // [Wxf; Wxs] rows 0..1535
  const _Float16* wcfs = wall + 6*per;    // [Wcf; Wcs] rows 0..1535
  floatx4 acc[4][4] = {};
  int m0 = blockIdx.x * 128;
  int ny = blockIdx.y;
  if (ny < 6){
    gemm_tile(xh, wph, m0, ny*128, As, Ws, acc);
    store_tile_f16(acc, xph, C_, bp, nullptr, m0, ny*128, 1);
  } else if (ny < 18){
    int n0 = (ny-6)*128;
    gemm_tile(xh,   wxfs, m0, n0, As, Ws, acc);
    gemm_tile(gate, wcfs, m0, n0, As, Ws, acc);
    store_tile_f16(acc, wgfs, K2_, bxf, bxs, m0, n0, 2);
  } else {
    int n0 = (ny-18)*128;
    gemm_tile(xh, wqk, m0, n0, As, Ws, acc);
    store_tile_f16(acc, qk, 256, nullptr, nullptr, m0, n0, 0);
  }
}

// stage 7: gf (sigmoid), gs (sigmoid), soma (tanh) -> f16 buffers
__global__ __launch_bounds__(256,4) void k_gemm_s7(
    const _Float16* __restrict__ cf, const _Float16* __restrict__ cs, const _Float16* __restrict__ xh,
    const _Float16* __restrict__ wall,
    const float* __restrict__ bf, const float* __restrict__ bs, const float* __restrict__ bso,
    _Float16* __restrict__ gfb, _Float16* __restrict__ gsb, _Float16* __restrict__ somab)
{
  __shared__ _Float16 As[128*64];
  __shared__ _Float16 Ws[128*64];
  const size_t per = (size_t)C_*C_;
  floatx4 acc[4][4] = {};
  int m0 = blockIdx.x * 128;
  int s = blockIdx.y / 6, nt = (blockIdx.y % 6) * 128;
  const _Float16* A = (s==0) ? cf : (s==1) ? cs : xh;
  const _Float16* W = wall + (size_t)(s+1)*per;   // Wfast, Wslow, Wsoma
  const float* bias = (s==0) ? bf : (s==1) ? bs : bso;
  _Float16* out = (s==0) ? gfb : (s==1) ? gsb : somab;
  gemm_tile(A, W, m0, nt, As, Ws, acc);
  store_tile_f16(acc, out, C_, bias, nullptr, m0, nt, (s==2) ? 1 : 2);
}

// ---------------- causal max-score (MFMA); qk row stride 256 (q at 0, k at 96) ----------------
#define SLDK 104
__global__ __launch_bounds__(256,3) void k_score(
    const _Float16* __restrict__ qk, unsigned* __restrict__ cgE)
{
  __shared__ _Float16 Qs[128*SLDK];
  __shared__ _Float16 Ks[128*SLDK];
  __shared__ float sred[256];
  int b = blockIdx.y;
  int p = blockIdx.x;
  int ti = (int)((sqrtf(8.f*p + 1.f) - 1.f)*0.5f);
  while ((ti+1)*(ti+2)/2 <= p) ++ti;
  while (ti*(ti+1)/2 > p) --ti;
  int sj = p - ti*(ti+1)/2;

  int tid = threadIdx.x;
  const _Float16* qg = qk + (size_t)(b*T_ + ti*128)*256;
  const _Float16* kg = qk + (size_t)(b*T_ + sj*128)*256 + 96;
  #pragma unroll
  for (int r = 0; r < 6; ++r){
    int ci = tid + r*256;
    int row = ci / 12, kp = ci % 12;
    *(uint4*)(&Qs[row*SLDK + kp*8]) = *(const uint4*)(qg + (size_t)row*256 + kp*8);
    *(uint4*)(&Ks[row*SLDK + kp*8]) = *(const uint4*)(kg + (size_t)row*256 + kp*8);
  }
  __syncthreads();

  int wave = tid >> 6, lane = tid & 63;
  int wr = wave >> 1, wc = wave & 1;
  int lr = lane & 15, lq = lane >> 4;
  floatx4 acc[4][4] = {};
  #pragma unroll
  for (int ks = 0; ks < 3; ++ks){
    half8 fa[4], fb[4];
    #pragma unroll
    for (int i = 0; i < 4; ++i){
      fa[i] = *(const half8*)(&Qs[(wr*64 + i*16 + lr)*SLDK + ks*32 + lq*8]);
      fb[i] = *(const half8*)(&Ks[(wc*64 + i*16 + lr)*SLDK + ks*32 + lq*8]);
    }
    #pragma unroll
    for (int i = 0; i < 4; ++i)
      #pragma unroll
      for (int j = 0; j < 4; ++j)
        acc[i][j] = __builtin_amdgcn_mfma_f32_16x16x32_f16(fa[i], fb[j], acc[i][j], 0, 0, 0);
  }
  const float scale = 0.10206207f;   // 96^-0.5
  #pragma unroll
  for (int i = 0; i < 4; ++i){
    #pragma unroll
    for (int r = 0; r < 4; ++r){
      int row64 = i*16 + lq*4 + r;          // row within this wr's 64-row band
      int tg = ti*128 + wr*64 + row64;
      float v = -3.0e38f;
      #pragma unroll
      for (int j = 0; j < 4; ++j){
        int sg = sj*128 + wc*64 + j*16 + lr;
        if (sg <= tg) v = fmaxf(v, acc[i][j][r]*scale);
      }
      #pragma unroll
      for (int off = 1; off < 16; off <<= 1) v = fmaxf(v, __shfl_xor(v, off, 16));
      if (lr == 0) sred[wr*128 + wc*64 + row64] = v;
    }
  }
  __syncthreads();
  // waves with wc==0 merge both wc bands and emit one atomic per row
  if (wc == 0 && lane < 64){
    int row64 = lane;
    float v = fmaxf(sred[wr*128 + row64], sred[wr*128 + 64 + row64]);
    int tg = ti*128 + wr*64 + row64;
    atomicMax(&cgE[(size_t)b*T_ + tg], enc_max(v));
  }
}

// ---------------- anchors ----------------
__global__ __launch_bounds__(256) void k_anchor(const float* __restrict__ x, const float* __restrict__ Wanc,
                        const float* __restrict__ banc, const float* __restrict__ scales,
                        float* __restrict__ delta){
  __shared__ float xs[NA_*C_];
  __shared__ float part[NA_*128];
  int b = blockIdx.y, ct = blockIdx.x;
  int tid = threadIdx.x;
  for (int i = tid; i < NA_*C_; i += 256){
    int n = i / C_, c = i - n*C_;
    xs[i] = x[(size_t)(b*T_ + n*(T_/NA_))*C_ + c];
  }
  __syncthreads();
  int col = ct*128 + (tid & 127), kh = tid >> 7;
  float acc[NA_] = {0,0,0,0,0,0,0,0};
  const float* wrow = Wanc + (size_t)col*C_ + kh*384;
  const float* xk = xs + kh*384;
  for (int k = 0; k < 384; ++k){
    float wv = wrow[k];
    #pragma unroll
    for (int n = 0; n < NA_; ++n) acc[n] += xk[n*C_ + k]*wv;
  }
  if (kh){
    #pragma unroll
    for (int n = 0; n < NA_; ++n) part[n*128 + (tid & 127)] = acc[n];
  }
  __syncthreads();
  if (!kh){
    float d = 0.f;
    float bv = banc[col];
    #pragma unroll
    for (int n = 0; n < NA_; ++n){
      float a = tanhf(acc[n] + part[n*128 + (tid & 127)] + bv);
      d += sigm(scales[n]) * a;
    }
    delta[(size_t)b*C_ + col] = d;
  }
}

// ---------------- fused blend + soma-mul + LayerNorm (192 thr, half4) ----------------
__global__ __launch_bounds__(192) void k_ln(const _Float16* __restrict__ gfb,
                                            const _Float16* __restrict__ gsb,
                                            const _Float16* __restrict__ somab,
                                            const float* __restrict__ blendr,
                                            const float* __restrict__ g, const float* __restrict__ be,
                                            float* __restrict__ out){
  int row = blockIdx.x;
  int tid = threadIdx.x;
  float bl = sigm(blendr[0]);
  size_t base = (size_t)row*C_ + tid*4;
  half4 gf4 = *(const half4*)(gfb + base);
  half4 gs4 = *(const half4*)(gsb + base);
  half4 so4 = *(const half4*)(somab + base);
  float v[4];
  #pragma unroll
  for (int i = 0; i < 4; ++i){
    float gf = (float)gf4[i], gs = (float)gs4[i], so = (float)so4[i];
    v[i] = so * (gf + bl*(gs - gf));
  }
  float s = v[0]+v[1]+v[2]+v[3];
  float ss = v[0]*v[0]+v[1]*v[1]+v[2]*v[2]+v[3]*v[3];
  #pragma unroll
  for (int off = 1; off < 64; off <<= 1){ s += __shfl_xor(s, off); ss += __shfl_xor(ss, off); }
  __shared__ float sb[6];
  int wave = tid >> 6, lane = tid & 63;
  if (lane == 0){ sb[wave] = s; sb[3+wave] = ss; }
  __syncthreads();
  s  = sb[0]+sb[1]+sb[2];
  ss = sb[3]+sb[4]+sb[5];
  float mu  = s * (1.f/C_);
  float var = ss * (1.f/C_) - mu*mu;
  float inv = rsqrtf(var + 1e-5f);
  float4 o;
  o.x = (v[0]-mu)*inv*g[tid*4+0] + be[tid*4+0];
  o.y = (v[1]-mu)*inv*g[tid*4+1] + be[tid*4+1];
  o.z = (v[2]-mu)*inv*g[tid*4+2] + be[tid*4+2];
  o.w = (v[3]-mu)*inv*g[tid*4+3] + be[tid*4+3];
  *(float4*)(out + base) = o;
}

// ---------------- launch ----------------
extern "C" void kernel_launch(void* const* d_in, const int* in_sizes, int n_in,
                              void* d_out, int out_size, void* d_ws, size_t ws_size,
                              hipStream_t stream){
  (void)in_sizes; (void)n_in; (void)out_size;
  const float* x        = (const float*)d_in[0];
  const float* tau_gate = (const float*)d_in[1];
  const float* tau_fast = (const float*)d_in[2];
  const float* tau_slow = (const float*)d_in[3];
  const float* Wp   = (const float*)d_in[4];  const float* bp    = (const float*)d_in[5];
  const float* Wxf  = (const float*)d_in[6];  const float* bxf   = (const float*)d_in[7];
  const float* Wxs  = (const float*)d_in[8];  const float* bxs   = (const float*)d_in[9];
  const float* Wcf  = (const float*)d_in[10]; const float* Wcs   = (const float*)d_in[11];
  const float* Wq   = (const float*)d_in[12]; const float* Wk    = (const float*)d_in[13];
  const float* Wfast= (const float*)d_in[14]; const float* bfast = (const float*)d_in[15];
  const float* Wslow= (const float*)d_in[16]; const float* bslow = (const float*)d_in[17];
  const float* Wsoma= (const float*)d_in[18]; const float* bsoma = (const float*)d_in[19];
  const float* Wanc = (const float*)d_in[20]; const float* banc  = (const float*)d_in[21];
  const float* ascl = (const float*)d_in[22]; const float* blendr= (const float*)d_in[23];
  const float* lng  = (const float*)d_in[24]; const float* lnb   = (const float*)d_in[25];
  float* out = (float*)d_out;

  char* w = (char*)d_ws;
  auto alloc = [&](size_t bytes)->void*{
    void* p = (void*)w; w += (bytes + 255) & ~(size_t)255; return p;
  };
  _Float16* xh    = (_Float16*)alloc((size_t)M_*C_*2);
  _Float16* wall  = (_Float16*)alloc((size_t)8*C_*C_*2);
  _Float16* wqk   = (_Float16*)alloc((size_t)256*C_*2);
  _Float16* gate  = (_Float16*)alloc((size_t)M_*C_*2);
  _Float16* xph   = (_Float16*)alloc((size_t)M_*C_*2);
  _Float16* wgfs  = (_Float16*)alloc((size_t)M_*K2_*2);
  _Float16* qk    = (_Float16*)alloc((size_t)M_*256*2);
  _Float16* csb   = (_Float16*)alloc((size_t)M_*C_*2);
  unsigned* cgE   = (unsigned*)alloc((size_t)M_*4);
  float* Sg = (float*)alloc((size_t)B_*NCH_*C_*4);
  float* Hg = (float*)alloc((size_t)B_*NCH_*C_*4);
  float* Sf = (float*)alloc((size_t)B_*NCH_*C_*4);
  float* Ss = (float*)alloc((size_t)B_*NCH_*C_*4);
  float* Hf = (float*)alloc((size_t)B_*NCH_*C_*4);
  float* Hs = (float*)alloc((size_t)B_*NCH_*C_*4);
  float* dlt = (float*)alloc((size_t)B_*C_*4);
  // reuse regions (stream-ordered, producer consumed before overwrite):
  _Float16* cfh   = gate;                      // cf overwrites gate (consumed by s3)
  _Float16* gfb   = wgfs;                      // gf/gs overwrite wgfs (consumed by fs_p3)
  _Float16* gsb   = wgfs + (size_t)M_*C_;
  _Float16* somab = xph;                       // soma overwrites xph (consumed by fs chain)
  if ((size_t)(w - (char*)d_ws) > ws_size) return;

  // 1) all weight casts + cgE init
  k_cast_w8<<<4896, 256, 0, stream>>>(Wp, Wfast, Wslow, Wsoma, Wxf, Wxs, Wcf, Wcs, Wq, Wk,
                                      wall, wqk, cgE);
  // 2) cast x -> xh + gate chunk sums
  k_castx_p1<<<B_*NCH_, 192, 0, stream>>>(x, tau_gate, xh, Sg);
  // 3) gate chunk-prefix
  k_p2_gate<<<B_*3, 256, 0, stream>>>(Sg, Hg, tau_gate);
  // 4) gate EMA stream -> gate
  k_gate_p3<<<B_*NCH_, 192, 0, stream>>>(xh, Hg, tau_gate, gate);
  // 5) stage 3: xp + wg (split-K) + q||k in one launch
  k_gemm_s3<<<dim3(M_/128, 20), 256, 0, stream>>>(xh, gate, wall, wqk,
                                                  bp, bxf, bxs, xph, wgfs, qk);
  // 6) causal max score
  k_score<<<dim3(136, B_), 256, 0, stream>>>(qk, cgE);
  // 7) anchors
  k_anchor<<<dim3(C_/128, B_), 256, 0, stream>>>(x, Wanc, banc, ascl, dlt);
  // 8) fast/slow EMA pass1
  k_fs_p1<<<B_*NCH_, 192, 0, stream>>>(xph, wgfs, tau_fast, tau_slow, Sf, Ss);
  // 9) fast/slow chunk-prefix (both)
  k_p2_fs<<<2*B_*3, 256, 0, stream>>>(Sf, Ss, Hf, Hs, tau_fast, tau_slow);
  // 10) fast/slow EMA stream (* cg + delta) -> cf/cs
  k_fs_p3<<<B_*NCH_, 192, 0, stream>>>(xph, wgfs, Hf, Hs, tau_fast, tau_slow,
                                       cgE, dlt, cfh, csb);
  // 11) stage 7: gf + gs + soma in one launch
  k_gemm_s7<<<dim3(M_/128, 18), 256, 0, stream>>>(cfh, csb, xh, wall,
                                                  bfast, bslow, bsoma, gfb, gsb, somab);
  // 12) fused blend + mul + LN
  k_ln<<<M_, 192, 0, stream>>>(gfb, gsb, somab, blendr, lng, lnb, out);
}

// Round 5
// 399.238 us; speedup vs baseline: 1.0640x; 1.0362x over previous
//
#include <hip/hip_runtime.h>
#include <math.h>

#define B_ 4
#define T_ 2048
#define C_ 768
#define DK_ 96
#define NA_ 8
#define M_ (B_*T_)      /* 8192 */
#define K2_ (2*C_)      /* 1536 */
#define NCH_ 256        /* EMA chunks per batch */
#define CK_ 8           /* EMA chunk len == tile row-chunk */

typedef __attribute__((ext_vector_type(8))) _Float16 half8;
typedef __attribute__((ext_vector_type(4))) _Float16 half4;
typedef __attribute__((ext_vector_type(4))) float floatx4;

#define AS1 __attribute__((address_space(1)))
#define AS3 __attribute__((address_space(3)))

__device__ __forceinline__ float sigm(float x){ return 1.f/(1.f + expf(-x)); }
__device__ __forceinline__ unsigned enc_max(float f){
  unsigned i = __float_as_uint(f);
  return (i & 0x80000000u) ? ~i : (i | 0x80000000u);
}
__device__ __forceinline__ float dec_max(unsigned u){
  unsigned i = (u & 0x80000000u) ? (u & 0x7FFFFFFFu) : ~u;
  return __uint_as_float(i);
}
__device__ __forceinline__ void gld16(const _Float16* g, _Float16* l){
  __builtin_amdgcn_global_load_lds((const AS1 unsigned int*)g, (AS3 unsigned int*)l, 16, 0, 0);
}

// ---------------- prep: weight casts + cgE init + x cast/Sg + anchors ----------------
#define NB0 4608   /* wall quads */
#define NB1 4896   /* + wqk/cgE */
#define NB2 5920   /* + castx_p1 (1024) */
#define NB3 5944   /* + anchor (24) */
__global__ __launch_bounds__(256) void k_prep(
    const float* __restrict__ x,
    const float* __restrict__ Wp, const float* __restrict__ Wfast,
    const float* __restrict__ Wslow, const float* __restrict__ Wsoma,
    const float* __restrict__ Wxf, const float* __restrict__ Wxs,
    const float* __restrict__ Wcf, const float* __restrict__ Wcs,
    const float* __restrict__ Wq, const float* __restrict__ Wk,
    const float* __restrict__ Wanc, const float* __restrict__ banc,
    const float* __restrict__ ascl, const float* __restrict__ tau_gate,
    _Float16* __restrict__ wall, _Float16* __restrict__ wqk,
    unsigned* __restrict__ cgE, _Float16* __restrict__ xh,
    float* __restrict__ Sg, float* __restrict__ dlt)
{
  __shared__ float xs[NA_*C_];
  __shared__ float part[NA_*128];
  int blk = blockIdx.x, tid = threadIdx.x;
  if (blk < NB0){
    int i = blk*256 + tid;
    const int per = (C_*C_)/4;
    int s = i / per, j = i - s*per;
    const float* src = s==0?Wp : s==1?Wfast : s==2?Wslow : s==3?Wsoma
                     : s==4?Wxf : s==5?Wxs : s==6?Wcf : Wcs;
    float4 v = ((const float4*)src)[j];
    half4 h = { (_Float16)v.x, (_Float16)v.y, (_Float16)v.z, (_Float16)v.w };
    ((half4*)wall)[(size_t)s*per + j] = h;
  } else if (blk < NB1){
    int sub = blk - NB0;
    if (sub >= 256){ cgE[(sub-256)*256 + tid] = 0u; return; }
    const float* src = (sub < 96) ? Wq + (size_t)sub*C_
                     : (sub < 192 ? Wk + (size_t)(sub-96)*C_ : nullptr);
    #pragma unroll
    for (int k = 0; k < 3; ++k){
      int c = tid + k*256;
      wqk[(size_t)sub*C_ + c] = src ? (_Float16)src[c] : (_Float16)0.f;
    }
  } else if (blk < NB2){
    if (tid >= 192) return;
    int sub = blk - NB1;
    float al = expf(-log1pf(expf(tau_gate[0])));
    int b = sub >> 8, ch = sub & (NCH_-1);
    int t0 = b*T_ + ch*CK_;
    float s0=0.f,s1=0.f,s2=0.f,s3=0.f;
    #pragma unroll
    for (int t = 0; t < CK_; ++t){
      float4 v = *(const float4*)(x + (size_t)(t0+t)*C_ + tid*4);
      half4 h = { (_Float16)v.x,(_Float16)v.y,(_Float16)v.z,(_Float16)v.w };
      *(half4*)(xh + (size_t)(t0+t)*C_ + tid*4) = h;
      s0 = al*s0 + v.x; s1 = al*s1 + v.y; s2 = al*s2 + v.z; s3 = al*s3 + v.w;
    }
    float4 sv = { s0,s1,s2,s3 };
    *(float4*)(Sg + (size_t)sub*C_ + tid*4) = sv;
  } else {
    int ab = blk - NB2;              // 0..23
    int ct = ab % 6, b = ab / 6;
    for (int i = tid; i < NA_*C_; i += 256){
      int n = i / C_, c = i - n*C_;
      xs[i] = x[(size_t)(b*T_ + n*(T_/NA_))*C_ + c];
    }
    __syncthreads();
    int col = ct*128 + (tid & 127), kh = tid >> 7;
    float acc[NA_] = {0,0,0,0,0,0,0,0};
    const float* wrow = Wanc + (size_t)col*C_ + kh*384;
    const float* xk = xs + kh*384;
    for (int k = 0; k < 384; ++k){
      float wv = wrow[k];
      #pragma unroll
      for (int n = 0; n < NA_; ++n) acc[n] += xk[n*C_ + k]*wv;
    }
    if (kh){
      #pragma unroll
      for (int n = 0; n < NA_; ++n) part[n*128 + (tid & 127)] = acc[n];
    }
    __syncthreads();
    if (!kh){
      float d = 0.f;
      float bv = banc[col];
      #pragma unroll
      for (int n = 0; n < NA_; ++n){
        float a = tanhf(acc[n] + part[n*128 + (tid & 127)] + bv);
        d += sigm(ascl[n]) * a;
      }
      dlt[(size_t)b*C_ + col] = d;
    }
  }
}

// ---------------- chunk-prefix scans (exclusive) ----------------
__global__ __launch_bounds__(256) void k_p2_gate(const float* __restrict__ S, float* __restrict__ H,
                                                 const float* __restrict__ tau){
  int blk = blockIdx.x;
  int b = blk / 3, c = (blk - b*3)*256 + threadIdx.x;
  float aCK = expf(-(float)CK_ * log1pf(expf(tau[0])));
  float h = 0.f;
  for (int ch = 0; ch < NCH_; ++ch){
    size_t idx = (size_t)(b*NCH_ + ch)*C_ + c;
    H[idx] = h;
    h = aCK*h + S[idx];
  }
}

__global__ __launch_bounds__(256) void k_p2_fs(const float* __restrict__ Sf, const float* __restrict__ Ss,
                                               float* __restrict__ Hf, float* __restrict__ Hs,
                                               const float* __restrict__ tf, const float* __restrict__ ts){
  int blk = blockIdx.x;
  int which = blk / 12, sub = blk - which*12;
  int b = sub / 3, c = (sub - b*3)*256 + threadIdx.x;
  const float* S = which ? Ss : Sf;
  float* H = which ? Hs : Hf;
  float aCK = expf(-(float)CK_ * log1pf(expf(which ? ts[0] : tf[0])));
  float h = 0.f;
  for (int ch = 0; ch < NCH_; ++ch){
    size_t idx = (size_t)(b*NCH_ + ch)*C_ + c;
    H[idx] = h;
    h = aCK*h + S[idx];
  }
}

// ---------------- GEMM building blocks (128x128, BK=64, async LDS + XOR swizzle) ----------------
__device__ __forceinline__ void stage_tile(const _Float16* __restrict__ src, int stride,
                                           int r0, int k0, _Float16* lds){
  int tid = threadIdx.x;
  int wave = tid >> 6, lane = tid & 63;
  #pragma unroll
  for (int it = 0; it < 4; ++it){
    int cb = it*256 + wave*64;
    int ck = cb + lane;
    int row = ck >> 3;
    int kp = (ck & 7) ^ (row & 7);
    gld16(src + (size_t)(r0+row)*stride + k0 + kp*8, lds + (size_t)cb*8);
  }
}

__device__ __forceinline__ void mfma_pass(const _Float16* As, const _Float16* Ws, floatx4 acc[4][4]){
  int tid = threadIdx.x;
  int wave = tid >> 6, lane = tid & 63;
  int wr = wave >> 1, wc = wave & 1;
  int lr = lane & 15, lq = lane >> 4;
  #pragma unroll
  for (int ks = 0; ks < 2; ++ks){
    half8 fa[4], fb[4];
    int off = (((ks*4 + lq) ^ (lr & 7)) << 3);
    #pragma unroll
    for (int i = 0; i < 4; ++i){
      fa[i] = *(const half8*)(As + (wr*64 + i*16 + lr)*64 + off);
      fb[i] = *(const half8*)(Ws + (wc*64 + i*16 + lr)*64 + off);
    }
    #pragma unroll
    for (int i = 0; i < 4; ++i)
      #pragma unroll
      for (int j = 0; j < 4; ++j)
        acc[i][j] = __builtin_amdgcn_mfma_f32_16x16x32_f16(fa[i], fb[j], acc[i][j], 0, 0, 0);
  }
}

__device__ __forceinline__ void store_tile_f16(floatx4 acc[4][4], _Float16* __restrict__ out, int ldo,
                                               const float* bias, const float* bias2,
                                               int m0, int n0, int act){
  int tid = threadIdx.x;
  int wave = tid >> 6, lane = tid & 63;
  int wr = wave >> 1, wc = wave & 1;
  int lr = lane & 15, lq = lane >> 4;
  #pragma unroll
  for (int i = 0; i < 4; ++i){
    #pragma unroll
    for (int j = 0; j < 4; ++j){
      int col = n0 + wc*64 + j*16 + lr;
      float bv = 0.f;
      if (bias) bv = (bias2 && col >= C_) ? bias2[col - C_] : bias[col];
      #pragma unroll
      for (int r = 0; r < 4; ++r){
        int rowm = m0 + wr*64 + i*16 + lq*4 + r;
        float z = acc[i][j][r] + bv;
        if (act == 1) z = tanhf(z);
        else if (act == 2) z = sigm(z);
        out[(size_t)rowm*ldo + col] = (_Float16)z;
      }
    }
  }
}

// stage 3: xp (tanh); wg = xh@[Wxf;Wxs] + EMA_inLDS(xh)@[Wcf;Wcs] (sigmoid); q||k
__global__ __launch_bounds__(256,4) void k_gemm_s3(
    const _Float16* __restrict__ xh, const _Float16* __restrict__ wall,
    const _Float16* __restrict__ wqk, const float* __restrict__ Hg,
    const float* __restrict__ tau_gate,
    const float* __restrict__ bp, const float* __restrict__ bxf, const float* __restrict__ bxs,
    _Float16* __restrict__ xph, _Float16* __restrict__ wgfs, _Float16* __restrict__ qk)
{
  __shared__ _Float16 As[128*64];
  __shared__ _Float16 Ws[128*64];
  const size_t per = (size_t)C_*C_;
  floatx4 acc[4][4] = {};
  int m0 = blockIdx.x * 128;
  int ny = blockIdx.y;
  int tid = threadIdx.x;
  if (ny < 6){
    for (int k0 = 0; k0 < C_; k0 += 64){
      stage_tile(xh, C_, m0, k0, As);
      stage_tile(wall, C_, ny*128, k0, Ws);
      asm volatile("s_waitcnt vmcnt(0)" ::: "memory");
      __syncthreads();
      mfma_pass(As, Ws, acc);
      __syncthreads();
    }
    store_tile_f16(acc, xph, C_, bp, nullptr, m0, ny*128, 1);
  } else if (ny < 18){
    int n0 = (ny-6)*128;
    float al = expf(-log1pf(expf(tau_gate[0])));
    int b = m0 >> 11;
    int ch0 = (m0 & (T_-1)) >> 3;
    int rc = tid >> 4, cc = (tid >> 1) & 7, hh = tid & 1;
    for (int k0 = 0; k0 < C_; k0 += 64){
      stage_tile(xh, C_, m0, k0, As);
      stage_tile(wall + 4*per, C_, n0, k0, Ws);   // [Wxf; Wxs]
      asm volatile("s_waitcnt vmcnt(0)" ::: "memory");
      __syncthreads();
      mfma_pass(As, Ws, acc);
      __syncthreads();
      stage_tile(wall + 6*per, C_, n0, k0, Ws);   // [Wcf; Wcs] (async over transform)
      // in-place EMA transform: As (xh slice) -> gate slice
      {
        float4 hv = *(const float4*)(Hg + ((size_t)b*NCH_ + ch0 + rc)*C_ + k0 + cc*8 + hh*4);
        float e0=hv.x, e1=hv.y, e2=hv.z, e3=hv.w;
        #pragma unroll
        for (int r = 0; r < 8; ++r){
          int idx = (rc*8+r)*64 + ((cc^r)<<3) + hh*4;
          half4 p = *(const half4*)(As+idx);
          e0 = al*e0 + (float)p[0];
          e1 = al*e1 + (float)p[1];
          e2 = al*e2 + (float)p[2];
          e3 = al*e3 + (float)p[3];
          half4 o = { (_Float16)e0,(_Float16)e1,(_Float16)e2,(_Float16)e3 };
          *(half4*)(As+idx) = o;
        }
      }
      asm volatile("s_waitcnt vmcnt(0)" ::: "memory");
      __syncthreads();
      mfma_pass(As, Ws, acc);
      __syncthreads();
    }
    store_tile_f16(acc, wgfs, K2_, bxf, bxs, m0, n0, 2);
  } else {
    int n0 = (ny-18)*128;
    for (int k0 = 0; k0 < C_; k0 += 64){
      stage_tile(xh, C_, m0, k0, As);
      stage_tile(wqk, C_, n0, k0, Ws);
      asm volatile("s_waitcnt vmcnt(0)" ::: "memory");
      __syncthreads();
      mfma_pass(As, Ws, acc);
      __syncthreads();
    }
    store_tile_f16(acc, qk, 256, nullptr, nullptr, m0, n0, 0);
  }
}

// stage 7: gf/gs (A = EMA_inLDS(xp*wg)*cg + delta, sigmoid), soma (A = xh, tanh)
__global__ __launch_bounds__(256,3) void k_gemm_s7(
    const _Float16* __restrict__ xph, const _Float16* __restrict__ wgfs,
    const _Float16* __restrict__ xh, const _Float16* __restrict__ wall,
    const float* __restrict__ Hf, const float* __restrict__ Hs,
    const float* __restrict__ tau_fast, const float* __restrict__ tau_slow,
    const unsigned* __restrict__ cgE, const float* __restrict__ dlt,
    const float* __restrict__ bf, const float* __restrict__ bs, const float* __restrict__ bso,
    _Float16* __restrict__ gfb, _Float16* __restrict__ gsb, _Float16* __restrict__ somab)
{
  __shared__ _Float16 As[128*64];
  __shared__ _Float16 Wg[128*64];
  __shared__ _Float16 Bs[128*64];
  __shared__ float cgv[128];
  const size_t per = (size_t)C_*C_;
  floatx4 acc[4][4] = {};
  int m0 = blockIdx.x * 128;
  int s = blockIdx.y / 6, nt = (blockIdx.y % 6) * 128;
  int tid = threadIdx.x;
  if (s == 2){
    for (int k0 = 0; k0 < C_; k0 += 64){
      stage_tile(xh, C_, m0, k0, As);
      stage_tile(wall + 3*per, C_, nt, k0, Bs);   // Wsoma
      asm volatile("s_waitcnt vmcnt(0)" ::: "memory");
      __syncthreads();
      mfma_pass(As, Bs, acc);
      __syncthreads();
    }
    store_tile_f16(acc, somab, C_, bso, nullptr, m0, nt, 1);
  } else {
    float al = expf(-log1pf(expf(s ? tau_slow[0] : tau_fast[0])));
    const float* Hx = s ? Hs : Hf;
    const _Float16* wsrc = wgfs + (s ? C_ : 0);
    const _Float16* Wm = wall + (size_t)(s+1)*per;  // Wfast / Wslow
    int b = m0 >> 11;
    int ch0 = (m0 & (T_-1)) >> 3;
    if (tid < 128) cgv[tid] = sigm(dec_max(cgE[m0 + tid]));
    __syncthreads();
    int rc = tid >> 4, cc = (tid >> 1) & 7, hh = tid & 1;
    for (int k0 = 0; k0 < C_; k0 += 64){
      stage_tile(xph, C_, m0, k0, As);
      stage_tile(wsrc, K2_, m0, k0, Wg);
      stage_tile(Wm, C_, nt, k0, Bs);
      asm volatile("s_waitcnt vmcnt(0)" ::: "memory");
      __syncthreads();
      // in-place transform: As = EMA(xp*wg)*cg + delta (f16)
      {
        float4 hv = *(const float4*)(Hx + ((size_t)b*NCH_ + ch0 + rc)*C_ + k0 + cc*8 + hh*4);
        float4 d  = *(const float4*)(dlt + (size_t)b*C_ + k0 + cc*8 + hh*4);
        float e0=hv.x, e1=hv.y, e2=hv.z, e3=hv.w;
        #pragma unroll
        for (int r = 0; r < 8; ++r){
          int idx = (rc*8+r)*64 + ((cc^r)<<3) + hh*4;
          half4 p = *(const half4*)(As+idx);
          half4 wv = *(const half4*)(Wg+idx);
          e0 = al*e0 + (float)p[0]*(float)wv[0];
          e1 = al*e1 + (float)p[1]*(float)wv[1];
          e2 = al*e2 + (float)p[2]*(float)wv[2];
          e3 = al*e3 + (float)p[3]*(float)wv[3];
          float cgr = cgv[rc*8 + r];
          half4 o = { (_Float16)(e0*cgr + d.x), (_Float16)(e1*cgr + d.y),
                      (_Float16)(e2*cgr + d.z), (_Float16)(e3*cgr + d.w) };
          *(half4*)(As+idx) = o;
        }
      }
      __syncthreads();
      mfma_pass(As, Bs, acc);
      __syncthreads();
    }
    store_tile_f16(acc, s ? gsb : gfb, C_, s ? bs : bf, nullptr, m0, nt, 2);
  }
}

// ---------------- score (544 blocks) + fs_p1 (1024 blocks) in one launch ----------------
#define SLDK 104
__global__ __launch_bounds__(256,2) void k_score_fs(
    const _Float16* __restrict__ qk, unsigned* __restrict__ cgE,
    const _Float16* __restrict__ xp, const _Float16* __restrict__ wgfs,
    const float* __restrict__ tf, const float* __restrict__ ts,
    float* __restrict__ Sf, float* __restrict__ Ss)
{
  __shared__ _Float16 Qs[128*SLDK];
  __shared__ _Float16 Ks[128*SLDK];
  __shared__ float sred[256];
  int idx = blockIdx.x;
  int tid = threadIdx.x;
  if (idx >= 544){
    // ---- fs_p1 ----
    if (tid >= 192) return;
    int f = idx - 544;
    float af = expf(-log1pf(expf(tf[0])));
    float as = expf(-log1pf(expf(ts[0])));
    int b = f >> 8, ch = f & (NCH_-1);
    int t0 = b*T_ + ch*CK_;
    float f0=0,f1=0,f2=0,f3=0, s0=0,s1=0,s2=0,s3=0;
    #pragma unroll
    for (int t = 0; t < CK_; ++t){
      half4 p = *(const half4*)(xp + (size_t)(t0+t)*C_ + tid*4);
      half4 wf = *(const half4*)(wgfs + (size_t)(t0+t)*K2_ + tid*4);
      half4 ws = *(const half4*)(wgfs + (size_t)(t0+t)*K2_ + C_ + tid*4);
      f0 = af*f0 + (float)p[0]*(float)wf[0]; s0 = as*s0 + (float)p[0]*(float)ws[0];
      f1 = af*f1 + (float)p[1]*(float)wf[1]; s1 = as*s1 + (float)p[1]*(float)ws[1];
      f2 = af*f2 + (float)p[2]*(float)wf[2]; s2 = as*s2 + (float)p[2]*(float)ws[2];
      f3 = af*f3 + (float)p[3]*(float)wf[3]; s3 = as*s3 + (float)p[3]*(float)ws[3];
    }
    float4 fv = { f0,f1,f2,f3 }, sv = { s0,s1,s2,s3 };
    *(float4*)(Sf + (size_t)f*C_ + tid*4) = fv;
    *(float4*)(Ss + (size_t)f*C_ + tid*4) = sv;
    return;
  }
  // ---- score ----
  int b = idx / 136;
  int p = idx - b*136;
  int ti = (int)((sqrtf(8.f*p + 1.f) - 1.f)*0.5f);
  while ((ti+1)*(ti+2)/2 <= p) ++ti;
  while (ti*(ti+1)/2 > p) --ti;
  int sj = p - ti*(ti+1)/2;

  const _Float16* qg = qk + (size_t)(b*T_ + ti*128)*256;
  const _Float16* kg = qk + (size_t)(b*T_ + sj*128)*256 + 96;
  #pragma unroll
  for (int r = 0; r < 6; ++r){
    int ci = tid + r*256;
    int row = ci / 12, kp = ci % 12;
    *(uint4*)(&Qs[row*SLDK + kp*8]) = *(const uint4*)(qg + (size_t)row*256 + kp*8);
    *(uint4*)(&Ks[row*SLDK + kp*8]) = *(const uint4*)(kg + (size_t)row*256 + kp*8);
  }
  __syncthreads();

  int wave = tid >> 6, lane = tid & 63;
  int wr = wave >> 1, wc = wave & 1;
  int lr = lane & 15, lq = lane >> 4;
  floatx4 acc[4][4] = {};
  #pragma unroll
  for (int ks = 0; ks < 3; ++ks){
    half8 fa[4], fb[4];
    #pragma unroll
    for (int i = 0; i < 4; ++i){
      fa[i] = *(const half8*)(&Qs[(wr*64 + i*16 + lr)*SLDK + ks*32 + lq*8]);
      fb[i] = *(const half8*)(&Ks[(wc*64 + i*16 + lr)*SLDK + ks*32 + lq*8]);
    }
    #pragma unroll
    for (int i = 0; i < 4; ++i)
      #pragma unroll
      for (int j = 0; j < 4; ++j)
        acc[i][j] = __builtin_amdgcn_mfma_f32_16x16x32_f16(fa[i], fb[j], acc[i][j], 0, 0, 0);
  }
  const float scale = 0.10206207f;   // 96^-0.5
  #pragma unroll
  for (int i = 0; i < 4; ++i){
    #pragma unroll
    for (int r = 0; r < 4; ++r){
      int row64 = i*16 + lq*4 + r;
      int tg = ti*128 + wr*64 + row64;
      float v = -3.0e38f;
      #pragma unroll
      for (int j = 0; j < 4; ++j){
        int sg = sj*128 + wc*64 + j*16 + lr;
        if (sg <= tg) v = fmaxf(v, acc[i][j][r]*scale);
      }
      #pragma unroll
      for (int off = 1; off < 16; off <<= 1) v = fmaxf(v, __shfl_xor(v, off, 16));
      if (lr == 0) sred[wr*128 + wc*64 + row64] = v;
    }
  }
  __syncthreads();
  if (wc == 0 && lane < 64){
    int row64 = lane;
    float v = fmaxf(sred[wr*128 + row64], sred[wr*128 + 64 + row64]);
    int tg = ti*128 + wr*64 + row64;
    atomicMax(&cgE[(size_t)b*T_ + tg], enc_max(v));
  }
}

// ---------------- fused blend + soma-mul + LayerNorm ----------------
__global__ __launch_bounds__(192) void k_ln(const _Float16* __restrict__ gfb,
                                            const _Float16* __restrict__ gsb,
                                            const _Float16* __restrict__ somab,
                                            const float* __restrict__ blendr,
                                            const float* __restrict__ g, const float* __restrict__ be,
                                            float* __restrict__ out){
  int row = blockIdx.x;
  int tid = threadIdx.x;
  float bl = sigm(blendr[0]);
  size_t base = (size_t)row*C_ + tid*4;
  half4 gf4 = *(const half4*)(gfb + base);
  half4 gs4 = *(const half4*)(gsb + base);
  half4 so4 = *(const half4*)(somab + base);
  float v[4];
  #pragma unroll
  for (int i = 0; i < 4; ++i){
    float gf = (float)gf4[i], gs = (float)gs4[i], so = (float)so4[i];
    v[i] = so * (gf + bl*(gs - gf));
  }
  float s = v[0]+v[1]+v[2]+v[3];
  float ss = v[0]*v[0]+v[1]*v[1]+v[2]*v[2]+v[3]*v[3];
  #pragma unroll
  for (int off = 1; off < 64; off <<= 1){ s += __shfl_xor(s, off); ss += __shfl_xor(ss, off); }
  __shared__ float sb[6];
  int wave = tid >> 6, lane = tid & 63;
  if (lane == 0){ sb[wave] = s; sb[3+wave] = ss; }
  __syncthreads();
  s  = sb[0]+sb[1]+sb[2];
  ss = sb[3]+sb[4]+sb[5];
  float mu  = s * (1.f/C_);
  float var = ss * (1.f/C_) - mu*mu;
  float inv = rsqrtf(var + 1e-5f);
  float4 o;
  o.x = (v[0]-mu)*inv*g[tid*4+0] + be[tid*4+0];
  o.y = (v[1]-mu)*inv*g[tid*4+1] + be[tid*4+1];
  o.z = (v[2]-mu)*inv*g[tid*4+2] + be[tid*4+2];
  o.w = (v[3]-mu)*inv*g[tid*4+3] + be[tid*4+3];
  *(float4*)(out + base) = o;
}

// ---------------- launch ----------------
extern "C" void kernel_launch(void* const* d_in, const int* in_sizes, int n_in,
                              void* d_out, int out_size, void* d_ws, size_t ws_size,
                              hipStream_t stream){
  (void)in_sizes; (void)n_in; (void)out_size;
  const float* x        = (const float*)d_in[0];
  const float* tau_gate = (const float*)d_in[1];
  const float* tau_fast = (const float*)d_in[2];
  const float* tau_slow = (const float*)d_in[3];
  const float* Wp   = (const float*)d_in[4];  const float* bp    = (const float*)d_in[5];
  const float* Wxf  = (const float*)d_in[6];  const float* bxf   = (const float*)d_in[7];
  const float* Wxs  = (const float*)d_in[8];  const float* bxs   = (const float*)d_in[9];
  const float* Wcf  = (const float*)d_in[10]; const float* Wcs   = (const float*)d_in[11];
  const float* Wq   = (const float*)d_in[12]; const float* Wk    = (const float*)d_in[13];
  const float* Wfast= (const float*)d_in[14]; const float* bfast = (const float*)d_in[15];
  const float* Wslow= (const float*)d_in[16]; const float* bslow = (const float*)d_in[17];
  const float* Wsoma= (const float*)d_in[18]; const float* bsoma = (const float*)d_in[19];
  const float* Wanc = (const float*)d_in[20]; const float* banc  = (const float*)d_in[21];
  const float* ascl = (const float*)d_in[22]; const float* blendr= (const float*)d_in[23];
  const float* lng  = (const float*)d_in[24]; const float* lnb   = (const float*)d_in[25];
  float* out = (float*)d_out;

  char* w = (char*)d_ws;
  auto alloc = [&](size_t bytes)->void*{
    void* p = (void*)w; w += (bytes + 255) & ~(size_t)255; return p;
  };
  _Float16* xh    = (_Float16*)alloc((size_t)M_*C_*2);
  _Float16* wall  = (_Float16*)alloc((size_t)8*C_*C_*2);
  _Float16* wqk   = (_Float16*)alloc((size_t)256*C_*2);
  _Float16* xph   = (_Float16*)alloc((size_t)M_*C_*2);
  _Float16* wgfs  = (_Float16*)alloc((size_t)M_*K2_*2);
  _Float16* qk    = (_Float16*)alloc((size_t)M_*256*2);
  _Float16* gfb   = (_Float16*)alloc((size_t)M_*C_*2);
  _Float16* gsb   = (_Float16*)alloc((size_t)M_*C_*2);
  _Float16* somab = (_Float16*)alloc((size_t)M_*C_*2);
  unsigned* cgE   = (unsigned*)alloc((size_t)M_*4);
  float* Sg = (float*)alloc((size_t)B_*NCH_*C_*4);
  float* Hg = (float*)alloc((size_t)B_*NCH_*C_*4);
  float* Ss = (float*)alloc((size_t)B_*NCH_*C_*4);
  float* Hs = (float*)alloc((size_t)B_*NCH_*C_*4);
  float* dlt = (float*)alloc((size_t)B_*C_*4);
  // aliases (stream-ordered reuse):
  float* Sf = Sg;    // Sg consumed by p2_gate (L2) before fs_p1 (L4) writes Sf
  float* Hf = Hg;    // Hg consumed by s3 (L3) before p2_fs (L5) writes Hf
  if ((size_t)(w - (char*)d_ws) > ws_size) return;

  // L1: prep (weights, cgE, x-cast + gate chunk sums, anchors)
  k_prep<<<NB3, 256, 0, stream>>>(x, Wp, Wfast, Wslow, Wsoma, Wxf, Wxs, Wcf, Wcs, Wq, Wk,
                                  Wanc, banc, ascl, tau_gate, wall, wqk, cgE, xh, Sg, dlt);
  // L2: gate chunk-prefix
  k_p2_gate<<<B_*3, 256, 0, stream>>>(Sg, Hg, tau_gate);
  // L3: stage 3 (xp + wg w/ in-LDS gate EMA + q||k)
  k_gemm_s3<<<dim3(M_/128, 20), 256, 0, stream>>>(xh, wall, wqk, Hg, tau_gate,
                                                  bp, bxf, bxs, xph, wgfs, qk);
  // L4: causal max score + fs chunk sums (independent, one launch)
  k_score_fs<<<544 + B_*NCH_, 256, 0, stream>>>(qk, cgE, xph, wgfs, tau_fast, tau_slow, Sf, Ss);
  // L5: fast/slow chunk-prefix
  k_p2_fs<<<2*B_*3, 256, 0, stream>>>(Sf, Ss, Hf, Hs, tau_fast, tau_slow);
  // L6: stage 7 (gf/gs w/ in-LDS cf/cs derivation + soma)
  k_gemm_s7<<<dim3(M_/128, 18), 256, 0, stream>>>(xph, wgfs, xh, wall, Hf, Hs,
                                                  tau_fast, tau_slow, cgE, dlt,
                                                  bfast, bslow, bsoma, gfb, gsb, somab);
  // L7: fused blend + mul + LN
  k_ln<<<M_, 192, 0, stream>>>(gfb, gsb, somab, blendr, lng, lnb, out);
}

// Round 6
// 388.378 us; speedup vs baseline: 1.0937x; 1.0280x over previous
//
#include <hip/hip_runtime.h>
#include <math.h>

#define B_ 4
#define T_ 2048
#define C_ 768
#define DK_ 96
#define NA_ 8
#define M_ (B_*T_)      /* 8192 */
#define K2_ (2*C_)      /* 1536 */
#define NCH_ 256        /* EMA chunks per batch */
#define CK_ 8           /* EMA chunk len == tile row-chunk */

typedef __attribute__((ext_vector_type(8))) _Float16 half8;
typedef __attribute__((ext_vector_type(4))) _Float16 half4;
typedef __attribute__((ext_vector_type(4))) float floatx4;

#define AS1 __attribute__((address_space(1)))
#define AS3 __attribute__((address_space(3)))

__device__ __forceinline__ float sigm(float x){ return 1.f/(1.f + expf(-x)); }
__device__ __forceinline__ unsigned enc_max(float f){
  unsigned i = __float_as_uint(f);
  return (i & 0x80000000u) ? ~i : (i | 0x80000000u);
}
__device__ __forceinline__ float dec_max(unsigned u){
  unsigned i = (u & 0x80000000u) ? (u & 0x7FFFFFFFu) : ~u;
  return __uint_as_float(i);
}
__device__ __forceinline__ void gld16(const _Float16* g, _Float16* l){
  __builtin_amdgcn_global_load_lds((const AS1 unsigned int*)g, (AS3 unsigned int*)l, 16, 0, 0);
}

// ---------------- prep: weight casts + cgE init + x cast/Sg + anchors ----------------
#define NB0 4608   /* wall quads */
#define NB1 4896   /* + wqk/cgE */
#define NB2 5920   /* + castx_p1 (1024) */
#define NB3 5944   /* + anchor (24) */
__global__ __launch_bounds__(256) void k_prep(
    const float* __restrict__ x,
    const float* __restrict__ Wp, const float* __restrict__ Wfast,
    const float* __restrict__ Wslow, const float* __restrict__ Wsoma,
    const float* __restrict__ Wxf, const float* __restrict__ Wxs,
    const float* __restrict__ Wcf, const float* __restrict__ Wcs,
    const float* __restrict__ Wq, const float* __restrict__ Wk,
    const float* __restrict__ Wanc, const float* __restrict__ banc,
    const float* __restrict__ ascl, const float* __restrict__ tau_gate,
    _Float16* __restrict__ wall, _Float16* __restrict__ wqk,
    unsigned* __restrict__ cgE, _Float16* __restrict__ xh,
    float* __restrict__ Sg, float* __restrict__ dlt)
{
  __shared__ float xs[NA_*C_];
  __shared__ float part[NA_*128];
  int blk = blockIdx.x, tid = threadIdx.x;
  if (blk < NB0){
    int i = blk*256 + tid;
    const int per = (C_*C_)/4;
    int s = i / per, j = i - s*per;
    const float* src = s==0?Wp : s==1?Wfast : s==2?Wslow : s==3?Wsoma
                     : s==4?Wxf : s==5?Wxs : s==6?Wcf : Wcs;
    float4 v = ((const float4*)src)[j];
    half4 h = { (_Float16)v.x, (_Float16)v.y, (_Float16)v.z, (_Float16)v.w };
    ((half4*)wall)[(size_t)s*per + j] = h;
  } else if (blk < NB1){
    int sub = blk - NB0;
    if (sub >= 256){ cgE[(sub-256)*256 + tid] = 0u; return; }
    const float* src = (sub < 96) ? Wq + (size_t)sub*C_
                     : (sub < 192 ? Wk + (size_t)(sub-96)*C_ : nullptr);
    #pragma unroll
    for (int k = 0; k < 3; ++k){
      int c = tid + k*256;
      wqk[(size_t)sub*C_ + c] = src ? (_Float16)src[c] : (_Float16)0.f;
    }
  } else if (blk < NB2){
    if (tid >= 192) return;
    int sub = blk - NB1;
    float al = expf(-log1pf(expf(tau_gate[0])));
    int b = sub >> 8, ch = sub & (NCH_-1);
    int t0 = b*T_ + ch*CK_;
    float s0=0.f,s1=0.f,s2=0.f,s3=0.f;
    #pragma unroll
    for (int t = 0; t < CK_; ++t){
      float4 v = *(const float4*)(x + (size_t)(t0+t)*C_ + tid*4);
      half4 h = { (_Float16)v.x,(_Float16)v.y,(_Float16)v.z,(_Float16)v.w };
      *(half4*)(xh + (size_t)(t0+t)*C_ + tid*4) = h;
      s0 = al*s0 + v.x; s1 = al*s1 + v.y; s2 = al*s2 + v.z; s3 = al*s3 + v.w;
    }
    float4 sv = { s0,s1,s2,s3 };
    *(float4*)(Sg + (size_t)sub*C_ + tid*4) = sv;
  } else {
    int ab = blk - NB2;              // 0..23
    int ct = ab % 6, b = ab / 6;
    for (int i = tid; i < NA_*C_; i += 256){
      int n = i / C_, c = i - n*C_;
      xs[i] = x[(size_t)(b*T_ + n*(T_/NA_))*C_ + c];
    }
    __syncthreads();
    int col = ct*128 + (tid & 127), kh = tid >> 7;
    float acc[NA_] = {0,0,0,0,0,0,0,0};
    const float* wrow = Wanc + (size_t)col*C_ + kh*384;
    const float* xk = xs + kh*384;
    for (int k = 0; k < 384; ++k){
      float wv = wrow[k];
      #pragma unroll
      for (int n = 0; n < NA_; ++n) acc[n] += xk[n*C_ + k]*wv;
    }
    if (kh){
      #pragma unroll
      for (int n = 0; n < NA_; ++n) part[n*128 + (tid & 127)] = acc[n];
    }
    __syncthreads();
    if (!kh){
      float d = 0.f;
      float bv = banc[col];
      #pragma unroll
      for (int n = 0; n < NA_; ++n){
        float a = tanhf(acc[n] + part[n*128 + (tid & 127)] + bv);
        d += sigm(ascl[n]) * a;
      }
      dlt[(size_t)b*C_ + col] = d;
    }
  }
}

// ---------------- chunk-prefix scans (exclusive) ----------------
__global__ __launch_bounds__(256) void k_p2_gate(const float* __restrict__ S, float* __restrict__ H,
                                                 const float* __restrict__ tau){
  int blk = blockIdx.x;
  int b = blk / 3, c = (blk - b*3)*256 + threadIdx.x;
  float aCK = expf(-(float)CK_ * log1pf(expf(tau[0])));
  float h = 0.f;
  for (int ch = 0; ch < NCH_; ++ch){
    size_t idx = (size_t)(b*NCH_ + ch)*C_ + c;
    H[idx] = h;
    h = aCK*h + S[idx];
  }
}

__global__ __launch_bounds__(256) void k_p2_fs(const float* __restrict__ Sf, const float* __restrict__ Ss,
                                               float* __restrict__ Hf, float* __restrict__ Hs,
                                               const float* __restrict__ tf, const float* __restrict__ ts){
  int blk = blockIdx.x;
  int which = blk / 12, sub = blk - which*12;
  int b = sub / 3, c = (sub - b*3)*256 + threadIdx.x;
  const float* S = which ? Ss : Sf;
  float* H = which ? Hs : Hf;
  float aCK = expf(-(float)CK_ * log1pf(expf(which ? ts[0] : tf[0])));
  float h = 0.f;
  for (int ch = 0; ch < NCH_; ++ch){
    size_t idx = (size_t)(b*NCH_ + ch)*C_ + c;
    H[idx] = h;
    h = aCK*h + S[idx];
  }
}

// ---------------- gate-EMA pass3: stream -> gate buffer (f16, stride C) ----------------
__global__ __launch_bounds__(192) void k_gate_p3(
    const _Float16* __restrict__ xh, const float* __restrict__ H,
    const float* __restrict__ tau, _Float16* __restrict__ gate){
  float al = expf(-log1pf(expf(tau[0])));
  int blk = blockIdx.x, b = blk >> 8, ch = blk & (NCH_-1);
  int c4 = threadIdx.x;
  float4 h0 = *(const float4*)(H + (size_t)blk*C_ + c4*4);
  float g0=h0.x, g1=h0.y, g2=h0.z, g3=h0.w;
  int t0 = b*T_ + ch*CK_;
  #pragma unroll
  for (int t = 0; t < CK_; ++t){
    half4 v = *(const half4*)(xh + (size_t)(t0+t)*C_ + c4*4);
    g0 = al*g0 + (float)v[0]; g1 = al*g1 + (float)v[1];
    g2 = al*g2 + (float)v[2]; g3 = al*g3 + (float)v[3];
    half4 o = { (_Float16)g0,(_Float16)g1,(_Float16)g2,(_Float16)g3 };
    *(half4*)(gate + (size_t)(t0+t)*C_ + c4*4) = o;
  }
}

// ---------------- GEMM building blocks (128x128, BK=64, async LDS + XOR swizzle) ----------------
__device__ __forceinline__ void stage_tile(const _Float16* __restrict__ src, int stride,
                                           int r0, int k0, _Float16* lds){
  int tid = threadIdx.x;
  int wave = tid >> 6, lane = tid & 63;
  #pragma unroll
  for (int it = 0; it < 4; ++it){
    int cb = it*256 + wave*64;
    int ck = cb + lane;
    int row = ck >> 3;
    int kp = (ck & 7) ^ (row & 7);
    gld16(src + (size_t)(r0+row)*stride + k0 + kp*8, lds + (size_t)cb*8);
  }
}

__device__ __forceinline__ void mfma_pass(const _Float16* As, const _Float16* Ws, floatx4 acc[4][4]){
  int tid = threadIdx.x;
  int wave = tid >> 6, lane = tid & 63;
  int wr = wave >> 1, wc = wave & 1;
  int lr = lane & 15, lq = lane >> 4;
  #pragma unroll
  for (int ks = 0; ks < 2; ++ks){
    half8 fa[4], fb[4];
    int off = (((ks*4 + lq) ^ (lr & 7)) << 3);
    #pragma unroll
    for (int i = 0; i < 4; ++i){
      fa[i] = *(const half8*)(As + (wr*64 + i*16 + lr)*64 + off);
      fb[i] = *(const half8*)(Ws + (wc*64 + i*16 + lr)*64 + off);
    }
    #pragma unroll
    for (int i = 0; i < 4; ++i)
      #pragma unroll
      for (int j = 0; j < 4; ++j)
        acc[i][j] = __builtin_amdgcn_mfma_f32_16x16x32_f16(fa[i], fb[j], acc[i][j], 0, 0, 0);
  }
}

__device__ __forceinline__ void store_tile_f16(floatx4 acc[4][4], _Float16* __restrict__ out, int ldo,
                                               const float* bias, const float* bias2,
                                               int m0, int n0, int act){
  int tid = threadIdx.x;
  int wave = tid >> 6, lane = tid & 63;
  int wr = wave >> 1, wc = wave & 1;
  int lr = lane & 15, lq = lane >> 4;
  #pragma unroll
  for (int i = 0; i < 4; ++i){
    #pragma unroll
    for (int j = 0; j < 4; ++j){
      int col = n0 + wc*64 + j*16 + lr;
      float bv = 0.f;
      if (bias) bv = (bias2 && col >= C_) ? bias2[col - C_] : bias[col];
      #pragma unroll
      for (int r = 0; r < 4; ++r){
        int rowm = m0 + wr*64 + i*16 + lq*4 + r;
        float z = acc[i][j][r] + bv;
        if (act == 1) z = tanhf(z);
        else if (act == 2) z = sigm(z);
        out[(size_t)rowm*ldo + col] = (_Float16)z;
      }
    }
  }
}

// stage 3: xp (tanh); wg = xh@[Wxf;Wxs] + gate@[Wcf;Wcs] (sigmoid, split-K); q||k
// 2-barrier K-loop (round-4 structure: 683 TF measured; in-LDS EMA variant regressed to 525 TF)
__global__ __launch_bounds__(256,4) void k_gemm_s3(
    const _Float16* __restrict__ xh, const _Float16* __restrict__ gate,
    const _Float16* __restrict__ wall, const _Float16* __restrict__ wqk,
    const float* __restrict__ bp, const float* __restrict__ bxf, const float* __restrict__ bxs,
    _Float16* __restrict__ xph, _Float16* __restrict__ wgfs, _Float16* __restrict__ qk)
{
  __shared__ _Float16 As[128*64];
  __shared__ _Float16 Ws[128*64];
  const size_t per = (size_t)C_*C_;
  floatx4 acc[4][4] = {};
  int m0 = blockIdx.x * 128;
  int ny = blockIdx.y;
  if (ny < 6){
    for (int k0 = 0; k0 < C_; k0 += 64){
      stage_tile(xh, C_, m0, k0, As);
      stage_tile(wall, C_, ny*128, k0, Ws);              // Wp
      asm volatile("s_waitcnt vmcnt(0)" ::: "memory");
      __syncthreads();
      mfma_pass(As, Ws, acc);
      __syncthreads();
    }
    store_tile_f16(acc, xph, C_, bp, nullptr, m0, ny*128, 1);
  } else if (ny < 18){
    int n0 = (ny-6)*128;
    for (int k0 = 0; k0 < C_; k0 += 64){
      stage_tile(xh, C_, m0, k0, As);
      stage_tile(wall + 4*per, C_, n0, k0, Ws);          // [Wxf; Wxs]
      asm volatile("s_waitcnt vmcnt(0)" ::: "memory");
      __syncthreads();
      mfma_pass(As, Ws, acc);
      __syncthreads();
    }
    for (int k0 = 0; k0 < C_; k0 += 64){
      stage_tile(gate, C_, m0, k0, As);
      stage_tile(wall + 6*per, C_, n0, k0, Ws);          // [Wcf; Wcs]
      asm volatile("s_waitcnt vmcnt(0)" ::: "memory");
      __syncthreads();
      mfma_pass(As, Ws, acc);
      __syncthreads();
    }
    store_tile_f16(acc, wgfs, K2_, bxf, bxs, m0, n0, 2);
  } else {
    int n0 = (ny-18)*128;
    for (int k0 = 0; k0 < C_; k0 += 64){
      stage_tile(xh, C_, m0, k0, As);
      stage_tile(wqk, C_, n0, k0, Ws);
      asm volatile("s_waitcnt vmcnt(0)" ::: "memory");
      __syncthreads();
      mfma_pass(As, Ws, acc);
      __syncthreads();
    }
    store_tile_f16(acc, qk, 256, nullptr, nullptr, m0, n0, 0);
  }
}

// stage 7: gf/gs (A = EMA_inLDS(xp*wg)*cg + delta, sigmoid), soma (A = xh, tanh)
__global__ __launch_bounds__(256,3) void k_gemm_s7(
    const _Float16* __restrict__ xph, const _Float16* __restrict__ wgfs,
    const _Float16* __restrict__ xh, const _Float16* __restrict__ wall,
    const float* __restrict__ Hf, const float* __restrict__ Hs,
    const float* __restrict__ tau_fast, const float* __restrict__ tau_slow,
    const unsigned* __restrict__ cgE, const float* __restrict__ dlt,
    const float* __restrict__ bf, const float* __restrict__ bs, const float* __restrict__ bso,
    _Float16* __restrict__ gfb, _Float16* __restrict__ gsb, _Float16* __restrict__ somab)
{
  __shared__ _Float16 As[128*64];
  __shared__ _Float16 Wg[128*64];
  __shared__ _Float16 Bs[128*64];
  __shared__ float cgv[128];
  const size_t per = (size_t)C_*C_;
  floatx4 acc[4][4] = {};
  int m0 = blockIdx.x * 128;
  int s = blockIdx.y / 6, nt = (blockIdx.y % 6) * 128;
  int tid = threadIdx.x;
  if (s == 2){
    for (int k0 = 0; k0 < C_; k0 += 64){
      stage_tile(xh, C_, m0, k0, As);
      stage_tile(wall + 3*per, C_, nt, k0, Bs);   // Wsoma
      asm volatile("s_waitcnt vmcnt(0)" ::: "memory");
      __syncthreads();
      mfma_pass(As, Bs, acc);
      __syncthreads();
    }
    store_tile_f16(acc, somab, C_, bso, nullptr, m0, nt, 1);
  } else {
    float al = expf(-log1pf(expf(s ? tau_slow[0] : tau_fast[0])));
    const float* Hx = s ? Hs : Hf;
    const _Float16* wsrc = wgfs + (s ? C_ : 0);
    const _Float16* Wm = wall + (size_t)(s+1)*per;  // Wfast / Wslow
    int b = m0 >> 11;
    int ch0 = (m0 & (T_-1)) >> 3;
    if (tid < 128) cgv[tid] = sigm(dec_max(cgE[m0 + tid]));
    __syncthreads();
    int rc = tid >> 4, cc = (tid >> 1) & 7, hh = tid & 1;
    for (int k0 = 0; k0 < C_; k0 += 64){
      stage_tile(xph, C_, m0, k0, As);
      stage_tile(wsrc, K2_, m0, k0, Wg);
      stage_tile(Wm, C_, nt, k0, Bs);
      asm volatile("s_waitcnt vmcnt(0)" ::: "memory");
      __syncthreads();
      // in-place transform: As = EMA(xp*wg)*cg + delta (f16)
      {
        float4 hv = *(const float4*)(Hx + ((size_t)b*NCH_ + ch0 + rc)*C_ + k0 + cc*8 + hh*4);
        float4 d  = *(const float4*)(dlt + (size_t)b*C_ + k0 + cc*8 + hh*4);
        float e0=hv.x, e1=hv.y, e2=hv.z, e3=hv.w;
        #pragma unroll
        for (int r = 0; r < 8; ++r){
          int idx = (rc*8+r)*64 + ((cc^r)<<3) + hh*4;
          half4 p = *(const half4*)(As+idx);
          half4 wv = *(const half4*)(Wg+idx);
          e0 = al*e0 + (float)p[0]*(float)wv[0];
          e1 = al*e1 + (float)p[1]*(float)wv[1];
          e2 = al*e2 + (float)p[2]*(float)wv[2];
          e3 = al*e3 + (float)p[3]*(float)wv[3];
          float cgr = cgv[rc*8 + r];
          half4 o = { (_Float16)(e0*cgr + d.x), (_Float16)(e1*cgr + d.y),
                      (_Float16)(e2*cgr + d.z), (_Float16)(e3*cgr + d.w) };
          *(half4*)(As+idx) = o;
        }
      }
      __syncthreads();
      mfma_pass(As, Bs, acc);
      __syncthreads();
    }
    store_tile_f16(acc, s ? gsb : gfb, C_, s ? bs : bf, nullptr, m0, nt, 2);
  }
}

// ---------------- score (544 blocks) + fs_p1 (1024 blocks) in one launch ----------------
#define SLDK 104
__global__ __launch_bounds__(256,2) void k_score_fs(
    const _Float16* __restrict__ qk, unsigned* __restrict__ cgE,
    const _Float16* __restrict__ xp, const _Float16* __restrict__ wgfs,
    const float* __restrict__ tf, const float* __restrict__ ts,
    float* __restrict__ Sf, float* __restrict__ Ss)
{
  __shared__ _Float16 Qs[128*SLDK];
  __shared__ _Float16 Ks[128*SLDK];
  __shared__ float sred[256];
  int idx = blockIdx.x;
  int tid = threadIdx.x;
  if (idx >= 544){
    // ---- fs_p1 ----
    if (tid >= 192) return;
    int f = idx - 544;
    float af = expf(-log1pf(expf(tf[0])));
    float as = expf(-log1pf(expf(ts[0])));
    int b = f >> 8, ch = f & (NCH_-1);
    int t0 = b*T_ + ch*CK_;
    float f0=0,f1=0,f2=0,f3=0, s0=0,s1=0,s2=0,s3=0;
    #pragma unroll
    for (int t = 0; t < CK_; ++t){
      half4 p = *(const half4*)(xp + (size_t)(t0+t)*C_ + tid*4);
      half4 wf = *(const half4*)(wgfs + (size_t)(t0+t)*K2_ + tid*4);
      half4 ws = *(const half4*)(wgfs + (size_t)(t0+t)*K2_ + C_ + tid*4);
      f0 = af*f0 + (float)p[0]*(float)wf[0]; s0 = as*s0 + (float)p[0]*(float)ws[0];
      f1 = af*f1 + (float)p[1]*(float)wf[1]; s1 = as*s1 + (float)p[1]*(float)ws[1];
      f2 = af*f2 + (float)p[2]*(float)wf[2]; s2 = as*s2 + (float)p[2]*(float)ws[2];
      f3 = af*f3 + (float)p[3]*(float)wf[3]; s3 = as*s3 + (float)p[3]*(float)ws[3];
    }
    float4 fv = { f0,f1,f2,f3 }, sv = { s0,s1,s2,s3 };
    *(float4*)(Sf + (size_t)f*C_ + tid*4) = fv;
    *(float4*)(Ss + (size_t)f*C_ + tid*4) = sv;
    return;
  }
  // ---- score ----
  int b = idx / 136;
  int p = idx - b*136;
  int ti = (int)((sqrtf(8.f*p + 1.f) - 1.f)*0.5f);
  while ((ti+1)*(ti+2)/2 <= p) ++ti;
  while (ti*(ti+1)/2 > p) --ti;
  int sj = p - ti*(ti+1)/2;

  const _Float16* qg = qk + (size_t)(b*T_ + ti*128)*256;
  const _Float16* kg = qk + (size_t)(b*T_ + sj*128)*256 + 96;
  #pragma unroll
  for (int r = 0; r < 6; ++r){
    int ci = tid + r*256;
    int row = ci / 12, kp = ci % 12;
    *(uint4*)(&Qs[row*SLDK + kp*8]) = *(const uint4*)(qg + (size_t)row*256 + kp*8);
    *(uint4*)(&Ks[row*SLDK + kp*8]) = *(const uint4*)(kg + (size_t)row*256 + kp*8);
  }
  __syncthreads();

  int wave = tid >> 6, lane = tid & 63;
  int wr = wave >> 1, wc = wave & 1;
  int lr = lane & 15, lq = lane >> 4;
  floatx4 acc[4][4] = {};
  #pragma unroll
  for (int ks = 0; ks < 3; ++ks){
    half8 fa[4], fb[4];
    #pragma unroll
    for (int i = 0; i < 4; ++i){
      fa[i] = *(const half8*)(&Qs[(wr*64 + i*16 + lr)*SLDK + ks*32 + lq*8]);
      fb[i] = *(const half8*)(&Ks[(wc*64 + i*16 + lr)*SLDK + ks*32 + lq*8]);
    }
    #pragma unroll
    for (int i = 0; i < 4; ++i)
      #pragma unroll
      for (int j = 0; j < 4; ++j)
        acc[i][j] = __builtin_amdgcn_mfma_f32_16x16x32_f16(fa[i], fb[j], acc[i][j], 0, 0, 0);
  }
  const float scale = 0.10206207f;   // 96^-0.5
  #pragma unroll
  for (int i = 0; i < 4; ++i){
    #pragma unroll
    for (int r = 0; r < 4; ++r){
      int row64 = i*16 + lq*4 + r;
      int tg = ti*128 + wr*64 + row64;
      float v = -3.0e38f;
      #pragma unroll
      for (int j = 0; j < 4; ++j){
        int sg = sj*128 + wc*64 + j*16 + lr;
        if (sg <= tg) v = fmaxf(v, acc[i][j][r]*scale);
      }
      #pragma unroll
      for (int off = 1; off < 16; off <<= 1) v = fmaxf(v, __shfl_xor(v, off, 16));
      if (lr == 0) sred[wr*128 + wc*64 + row64] = v;
    }
  }
  __syncthreads();
  if (wc == 0 && lane < 64){
    int row64 = lane;
    float v = fmaxf(sred[wr*128 + row64], sred[wr*128 + 64 + row64]);
    int tg = ti*128 + wr*64 + row64;
    atomicMax(&cgE[(size_t)b*T_ + tg], enc_max(v));
  }
}

// ---------------- fused blend + soma-mul + LayerNorm ----------------
__global__ __launch_bounds__(192) void k_ln(const _Float16* __restrict__ gfb,
                                            const _Float16* __restrict__ gsb,
                                            const _Float16* __restrict__ somab,
                                            const float* __restrict__ blendr,
                                            const float* __restrict__ g, const float* __restrict__ be,
                                            float* __restrict__ out){
  int row = blockIdx.x;
  int tid = threadIdx.x;
  float bl = sigm(blendr[0]);
  size_t base = (size_t)row*C_ + tid*4;
  half4 gf4 = *(const half4*)(gfb + base);
  half4 gs4 = *(const half4*)(gsb + base);
  half4 so4 = *(const half4*)(somab + base);
  float v[4];
  #pragma unroll
  for (int i = 0; i < 4; ++i){
    float gf = (float)gf4[i], gs = (float)gs4[i], so = (float)so4[i];
    v[i] = so * (gf + bl*(gs - gf));
  }
  float s = v[0]+v[1]+v[2]+v[3];
  float ss = v[0]*v[0]+v[1]*v[1]+v[2]*v[2]+v[3]*v[3];
  #pragma unroll
  for (int off = 1; off < 64; off <<= 1){ s += __shfl_xor(s, off); ss += __shfl_xor(ss, off); }
  __shared__ float sb[6];
  int wave = tid >> 6, lane = tid & 63;
  if (lane == 0){ sb[wave] = s; sb[3+wave] = ss; }
  __syncthreads();
  s  = sb[0]+sb[1]+sb[2];
  ss = sb[3]+sb[4]+sb[5];
  float mu  = s * (1.f/C_);
  float var = ss * (1.f/C_) - mu*mu;
  float inv = rsqrtf(var + 1e-5f);
  float4 o;
  o.x = (v[0]-mu)*inv*g[tid*4+0] + be[tid*4+0];
  o.y = (v[1]-mu)*inv*g[tid*4+1] + be[tid*4+1];
  o.z = (v[2]-mu)*inv*g[tid*4+2] + be[tid*4+2];
  o.w = (v[3]-mu)*inv*g[tid*4+3] + be[tid*4+3];
  *(float4*)(out + base) = o;
}

// ---------------- launch ----------------
extern "C" void kernel_launch(void* const* d_in, const int* in_sizes, int n_in,
                              void* d_out, int out_size, void* d_ws, size_t ws_size,
                              hipStream_t stream){
  (void)in_sizes; (void)n_in; (void)out_size;
  const float* x        = (const float*)d_in[0];
  const float* tau_gate = (const float*)d_in[1];
  const float* tau_fast = (const float*)d_in[2];
  const float* tau_slow = (const float*)d_in[3];
  const float* Wp   = (const float*)d_in[4];  const float* bp    = (const float*)d_in[5];
  const float* Wxf  = (const float*)d_in[6];  const float* bxf   = (const float*)d_in[7];
  const float* Wxs  = (const float*)d_in[8];  const float* bxs   = (const float*)d_in[9];
  const float* Wcf  = (const float*)d_in[10]; const float* Wcs   = (const float*)d_in[11];
  const float* Wq   = (const float*)d_in[12]; const float* Wk    = (const float*)d_in[13];
  const float* Wfast= (const float*)d_in[14]; const float* bfast = (const float*)d_in[15];
  const float* Wslow= (const float*)d_in[16]; const float* bslow = (const float*)d_in[17];
  const float* Wsoma= (const float*)d_in[18]; const float* bsoma = (const float*)d_in[19];
  const float* Wanc = (const float*)d_in[20]; const float* banc  = (const float*)d_in[21];
  const float* ascl = (const float*)d_in[22]; const float* blendr= (const float*)d_in[23];
  const float* lng  = (const float*)d_in[24]; const float* lnb   = (const float*)d_in[25];
  float* out = (float*)d_out;

  char* w = (char*)d_ws;
  auto alloc = [&](size_t bytes)->void*{
    void* p = (void*)w; w += (bytes + 255) & ~(size_t)255; return p;
  };
  _Float16* xh    = (_Float16*)alloc((size_t)M_*C_*2);
  _Float16* wall  = (_Float16*)alloc((size_t)8*C_*C_*2);
  _Float16* wqk   = (_Float16*)alloc((size_t)256*C_*2);
  _Float16* xph   = (_Float16*)alloc((size_t)M_*C_*2);
  _Float16* wgfs  = (_Float16*)alloc((size_t)M_*K2_*2);
  _Float16* qk    = (_Float16*)alloc((size_t)M_*256*2);
  _Float16* gfb   = (_Float16*)alloc((size_t)M_*C_*2);
  _Float16* gsb   = (_Float16*)alloc((size_t)M_*C_*2);
  _Float16* somab = (_Float16*)alloc((size_t)M_*C_*2);
  unsigned* cgE   = (unsigned*)alloc((size_t)M_*4);
  float* Sg = (float*)alloc((size_t)B_*NCH_*C_*4);
  float* Hg = (float*)alloc((size_t)B_*NCH_*C_*4);
  float* Ss = (float*)alloc((size_t)B_*NCH_*C_*4);
  float* Hs = (float*)alloc((size_t)B_*NCH_*C_*4);
  float* dlt = (float*)alloc((size_t)B_*C_*4);
  // aliases (stream-ordered reuse):
  _Float16* gate = gfb;  // gate consumed by s3 (L4) before s7 (L8) writes gfb
  float* Sf = Sg;        // Sg consumed by p2_gate (L2) before score_fs (L5) writes Sf
  float* Hf = Hg;        // Hg consumed by gate_p3 (L3) before p2_fs (L6) writes Hf
  if ((size_t)(w - (char*)d_ws) > ws_size) return;

  // L1: prep (weights, cgE, x-cast + gate chunk sums, anchors)
  k_prep<<<NB3, 256, 0, stream>>>(x, Wp, Wfast, Wslow, Wsoma, Wxf, Wxs, Wcf, Wcs, Wq, Wk,
                                  Wanc, banc, ascl, tau_gate, wall, wqk, cgE, xh, Sg, dlt);
  // L2: gate chunk-prefix
  k_p2_gate<<<B_*3, 256, 0, stream>>>(Sg, Hg, tau_gate);
  // L3: gate EMA stream -> gate buffer
  k_gate_p3<<<B_*NCH_, 192, 0, stream>>>(xh, Hg, tau_gate, gate);
  // L4: stage 3 (xp + wg split-K + q||k), clean 2-barrier K-loop
  k_gemm_s3<<<dim3(M_/128, 20), 256, 0, stream>>>(xh, gate, wall, wqk,
                                                  bp, bxf, bxs, xph, wgfs, qk);
  // L5: causal max score + fs chunk sums (independent, one launch)
  k_score_fs<<<544 + B_*NCH_, 256, 0, stream>>>(qk, cgE, xph, wgfs, tau_fast, tau_slow, Sf, Ss);
  // L6: fast/slow chunk-prefix
  k_p2_fs<<<2*B_*3, 256, 0, stream>>>(Sf, Ss, Hf, Hs, tau_fast, tau_slow);
  // L7: stage 7 (gf/gs w/ in-LDS cf/cs derivation + soma)
  k_gemm_s7<<<dim3(M_/128, 18), 256, 0, stream>>>(xph, wgfs, xh, wall, Hf, Hs,
                                                  tau_fast, tau_slow, cgE, dlt,
                                                  bfast, bslow, bsoma, gfb, gsb, somab);
  // L8: fused blend + mul + LN
  k_ln<<<M_, 192, 0, stream>>>(gfb, gsb, somab, blendr, lng, lnb, out);
}

// Round 7
// 351.642 us; speedup vs baseline: 1.2080x; 1.1045x over previous
//
#include <hip/hip_runtime.h>
#include <math.h>

#define B_ 4
#define T_ 2048
#define C_ 768
#define DK_ 96
#define NA_ 8
#define M_ (B_*T_)      /* 8192 */
#define K2_ (2*C_)      /* 1536 */
#define NCH_ 256        /* EMA chunks per batch */
#define CK_ 8           /* EMA chunk len == tile row-chunk */

typedef __attribute__((ext_vector_type(8))) _Float16 half8;
typedef __attribute__((ext_vector_type(4))) _Float16 half4;
typedef __attribute__((ext_vector_type(4))) float floatx4;

#define AS1 __attribute__((address_space(1)))
#define AS3 __attribute__((address_space(3)))

__device__ __forceinline__ float sigm(float x){ return 1.f/(1.f + expf(-x)); }
__device__ __forceinline__ unsigned enc_max(float f){
  unsigned i = __float_as_uint(f);
  return (i & 0x80000000u) ? ~i : (i | 0x80000000u);
}
__device__ __forceinline__ float dec_max(unsigned u){
  unsigned i = (u & 0x80000000u) ? (u & 0x7FFFFFFFu) : ~u;
  return __uint_as_float(i);
}
__device__ __forceinline__ void gld16(const _Float16* g, _Float16* l){
  __builtin_amdgcn_global_load_lds((const AS1 unsigned int*)g, (AS3 unsigned int*)l, 16, 0, 0);
}

// ---------------- L1: cast x -> xh + gate chunk sums ----------------
__global__ __launch_bounds__(192) void k_castx(
    const float* __restrict__ x, const float* __restrict__ tau,
    _Float16* __restrict__ xh, float* __restrict__ Sg){
  float al = expf(-log1pf(expf(tau[0])));
  int blk = blockIdx.x, b = blk >> 8, ch = blk & (NCH_-1);
  int t0 = b*T_ + ch*CK_;
  int c4 = threadIdx.x;
  float s0=0.f,s1=0.f,s2=0.f,s3=0.f;
  #pragma unroll
  for (int t = 0; t < CK_; ++t){
    float4 v = *(const float4*)(x + (size_t)(t0+t)*C_ + c4*4);
    half4 h = { (_Float16)v.x,(_Float16)v.y,(_Float16)v.z,(_Float16)v.w };
    *(half4*)(xh + (size_t)(t0+t)*C_ + c4*4) = h;
    s0 = al*s0 + v.x; s1 = al*s1 + v.y; s2 = al*s2 + v.z; s3 = al*s3 + v.w;
  }
  float4 sv = { s0,s1,s2,s3 };
  *(float4*)(Sg + (size_t)blk*C_ + c4*4) = sv;
}

// ---------------- L2: weight casts + cgE init + anchors + gate chunk-prefix ----------------
#define NB0 4608   /* wall quads */
#define NB1 4896   /* + wqk/cgE (288) */
#define NB2 4920   /* + anchor (24) */
#define NB3 4932   /* + p2_gate (12) */
__global__ __launch_bounds__(256) void k_prep(
    const float* __restrict__ x,
    const float* __restrict__ Wp, const float* __restrict__ Wfast,
    const float* __restrict__ Wslow, const float* __restrict__ Wsoma,
    const float* __restrict__ Wxf, const float* __restrict__ Wxs,
    const float* __restrict__ Wcf, const float* __restrict__ Wcs,
    const float* __restrict__ Wq, const float* __restrict__ Wk,
    const float* __restrict__ Wanc, const float* __restrict__ banc,
    const float* __restrict__ ascl, const float* __restrict__ tau_gate,
    const float* __restrict__ Sg,
    _Float16* __restrict__ wall, _Float16* __restrict__ wqk,
    unsigned* __restrict__ cgE, float* __restrict__ Hg, float* __restrict__ dlt)
{
  __shared__ float xs[NA_*C_];
  __shared__ float part[NA_*128];
  int blk = blockIdx.x, tid = threadIdx.x;
  if (blk < NB0){
    int i = blk*256 + tid;
    const int per = (C_*C_)/4;
    int s = i / per, j = i - s*per;
    const float* src = s==0?Wp : s==1?Wfast : s==2?Wslow : s==3?Wsoma
                     : s==4?Wxf : s==5?Wxs : s==6?Wcf : Wcs;
    float4 v = ((const float4*)src)[j];
    half4 h = { (_Float16)v.x, (_Float16)v.y, (_Float16)v.z, (_Float16)v.w };
    ((half4*)wall)[(size_t)s*per + j] = h;
  } else if (blk < NB1){
    int sub = blk - NB0;
    if (sub >= 256){ cgE[(sub-256)*256 + tid] = 0u; return; }
    const float* src = (sub < 96) ? Wq + (size_t)sub*C_
                     : (sub < 192 ? Wk + (size_t)(sub-96)*C_ : nullptr);
    #pragma unroll
    for (int k = 0; k < 3; ++k){
      int c = tid + k*256;
      wqk[(size_t)sub*C_ + c] = src ? (_Float16)src[c] : (_Float16)0.f;
    }
  } else if (blk < NB2){
    int ab = blk - NB1;              // 0..23
    int ct = ab % 6, b = ab / 6;
    for (int i = tid; i < NA_*C_; i += 256){
      int n = i / C_, c = i - n*C_;
      xs[i] = x[(size_t)(b*T_ + n*(T_/NA_))*C_ + c];
    }
    __syncthreads();
    int col = ct*128 + (tid & 127), kh = tid >> 7;
    float acc[NA_] = {0,0,0,0,0,0,0,0};
    const float* wrow = Wanc + (size_t)col*C_ + kh*384;
    const float* xk = xs + kh*384;
    for (int k = 0; k < 384; ++k){
      float wv = wrow[k];
      #pragma unroll
      for (int n = 0; n < NA_; ++n) acc[n] += xk[n*C_ + k]*wv;
    }
    if (kh){
      #pragma unroll
      for (int n = 0; n < NA_; ++n) part[n*128 + (tid & 127)] = acc[n];
    }
    __syncthreads();
    if (!kh){
      float d = 0.f;
      float bv = banc[col];
      #pragma unroll
      for (int n = 0; n < NA_; ++n){
        float a = tanhf(acc[n] + part[n*128 + (tid & 127)] + bv);
        d += sigm(ascl[n]) * a;
      }
      dlt[(size_t)b*C_ + col] = d;
    }
  } else {
    // gate chunk-prefix (needs Sg from L1)
    int sub = blk - NB2;             // 0..11
    int b = sub / 3, c = (sub - b*3)*256 + tid;
    float aCK = expf(-(float)CK_ * log1pf(expf(tau_gate[0])));
    float h = 0.f;
    for (int ch = 0; ch < NCH_; ++ch){
      size_t idx = (size_t)(b*NCH_ + ch)*C_ + c;
      Hg[idx] = h;
      h = aCK*h + Sg[idx];
    }
  }
}

__global__ __launch_bounds__(256) void k_p2_fs(const float* __restrict__ Sf, const float* __restrict__ Ss,
                                               float* __restrict__ Hf, float* __restrict__ Hs,
                                               const float* __restrict__ tf, const float* __restrict__ ts){
  int blk = blockIdx.x;
  int which = blk / 12, sub = blk - which*12;
  int b = sub / 3, c = (sub - b*3)*256 + threadIdx.x;
  const float* S = which ? Ss : Sf;
  float* H = which ? Hs : Hf;
  float aCK = expf(-(float)CK_ * log1pf(expf(which ? ts[0] : tf[0])));
  float h = 0.f;
  for (int ch = 0; ch < NCH_; ++ch){
    size_t idx = (size_t)(b*NCH_ + ch)*C_ + c;
    H[idx] = h;
    h = aCK*h + S[idx];
  }
}

// ---------------- gate-EMA pass3: stream -> gate buffer (f16, stride C) ----------------
__global__ __launch_bounds__(192) void k_gate_p3(
    const _Float16* __restrict__ xh, const float* __restrict__ H,
    const float* __restrict__ tau, _Float16* __restrict__ gate){
  float al = expf(-log1pf(expf(tau[0])));
  int blk = blockIdx.x, b = blk >> 8, ch = blk & (NCH_-1);
  int c4 = threadIdx.x;
  float4 h0 = *(const float4*)(H + (size_t)blk*C_ + c4*4);
  float g0=h0.x, g1=h0.y, g2=h0.z, g3=h0.w;
  int t0 = b*T_ + ch*CK_;
  #pragma unroll
  for (int t = 0; t < CK_; ++t){
    half4 v = *(const half4*)(xh + (size_t)(t0+t)*C_ + c4*4);
    g0 = al*g0 + (float)v[0]; g1 = al*g1 + (float)v[1];
    g2 = al*g2 + (float)v[2]; g3 = al*g3 + (float)v[3];
    half4 o = { (_Float16)g0,(_Float16)g1,(_Float16)g2,(_Float16)g3 };
    *(half4*)(gate + (size_t)(t0+t)*C_ + c4*4) = o;
  }
}

// ---------------- GEMM building blocks (128x128, BK=64, async LDS + XOR swizzle) ----------------
__device__ __forceinline__ void stage_tile(const _Float16* __restrict__ src, int stride,
                                           int r0, int k0, _Float16* lds){
  int tid = threadIdx.x;
  int wave = tid >> 6, lane = tid & 63;
  #pragma unroll
  for (int it = 0; it < 4; ++it){
    int cb = it*256 + wave*64;
    int ck = cb + lane;
    int row = ck >> 3;
    int kp = (ck & 7) ^ (row & 7);
    gld16(src + (size_t)(r0+row)*stride + k0 + kp*8, lds + (size_t)cb*8);
  }
}

__device__ __forceinline__ void mfma_pass(const _Float16* As, const _Float16* Ws, floatx4 acc[4][4]){
  int tid = threadIdx.x;
  int wave = tid >> 6, lane = tid & 63;
  int wr = wave >> 1, wc = wave & 1;
  int lr = lane & 15, lq = lane >> 4;
  #pragma unroll
  for (int ks = 0; ks < 2; ++ks){
    half8 fa[4], fb[4];
    int off = (((ks*4 + lq) ^ (lr & 7)) << 3);
    #pragma unroll
    for (int i = 0; i < 4; ++i){
      fa[i] = *(const half8*)(As + (wr*64 + i*16 + lr)*64 + off);
      fb[i] = *(const half8*)(Ws + (wc*64 + i*16 + lr)*64 + off);
    }
    #pragma unroll
    for (int i = 0; i < 4; ++i)
      #pragma unroll
      for (int j = 0; j < 4; ++j)
        acc[i][j] = __builtin_amdgcn_mfma_f32_16x16x32_f16(fa[i], fb[j], acc[i][j], 0, 0, 0);
  }
}

__device__ __forceinline__ void store_tile_f16(floatx4 acc[4][4], _Float16* __restrict__ out, int ldo,
                                               const float* bias, const float* bias2,
                                               int m0, int n0, int act){
  int tid = threadIdx.x;
  int wave = tid >> 6, lane = tid & 63;
  int wr = wave >> 1, wc = wave & 1;
  int lr = lane & 15, lq = lane >> 4;
  #pragma unroll
  for (int i = 0; i < 4; ++i){
    #pragma unroll
    for (int j = 0; j < 4; ++j){
      int col = n0 + wc*64 + j*16 + lr;
      float bv = 0.f;
      if (bias) bv = (bias2 && col >= C_) ? bias2[col - C_] : bias[col];
      #pragma unroll
      for (int r = 0; r < 4; ++r){
        int rowm = m0 + wr*64 + i*16 + lq*4 + r;
        float z = acc[i][j][r] + bv;
        if (act == 1) z = tanhf(z);
        else if (act == 2) z = sigm(z);
        out[(size_t)rowm*ldo + col] = (_Float16)z;
      }
    }
  }
}

// stage 3: xp (tanh); wg = xh@[Wxf;Wxs] + gate@[Wcf;Wcs] (sigmoid, split-K); q||k
__global__ __launch_bounds__(256,4) void k_gemm_s3(
    const _Float16* __restrict__ xh, const _Float16* __restrict__ gate,
    const _Float16* __restrict__ wall, const _Float16* __restrict__ wqk,
    const float* __restrict__ bp, const float* __restrict__ bxf, const float* __restrict__ bxs,
    _Float16* __restrict__ xph, _Float16* __restrict__ wgfs, _Float16* __restrict__ qk)
{
  __shared__ _Float16 As[128*64];
  __shared__ _Float16 Ws[128*64];
  const size_t per = (size_t)C_*C_;
  floatx4 acc[4][4] = {};
  int m0 = blockIdx.x * 128;
  int ny = blockIdx.y;
  if (ny < 6){
    for (int k0 = 0; k0 < C_; k0 += 64){
      stage_tile(xh, C_, m0, k0, As);
      stage_tile(wall, C_, ny*128, k0, Ws);              // Wp
      asm volatile("s_waitcnt vmcnt(0)" ::: "memory");
      __syncthreads();
      mfma_pass(As, Ws, acc);
      __syncthreads();
    }
    store_tile_f16(acc, xph, C_, bp, nullptr, m0, ny*128, 1);
  } else if (ny < 18){
    int n0 = (ny-6)*128;
    for (int k0 = 0; k0 < C_; k0 += 64){
      stage_tile(xh, C_, m0, k0, As);
      stage_tile(wall + 4*per, C_, n0, k0, Ws);          // [Wxf; Wxs]
      asm volatile("s_waitcnt vmcnt(0)" ::: "memory");
      __syncthreads();
      mfma_pass(As, Ws, acc);
      __syncthreads();
    }
    for (int k0 = 0; k0 < C_; k0 += 64){
      stage_tile(gate, C_, m0, k0, As);
      stage_tile(wall + 6*per, C_, n0, k0, Ws);          // [Wcf; Wcs]
      asm volatile("s_waitcnt vmcnt(0)" ::: "memory");
      __syncthreads();
      mfma_pass(As, Ws, acc);
      __syncthreads();
    }
    store_tile_f16(acc, wgfs, K2_, bxf, bxs, m0, n0, 2);
  } else {
    int n0 = (ny-18)*128;
    for (int k0 = 0; k0 < C_; k0 += 64){
      stage_tile(xh, C_, m0, k0, As);
      stage_tile(wqk, C_, n0, k0, Ws);
      asm volatile("s_waitcnt vmcnt(0)" ::: "memory");
      __syncthreads();
      mfma_pass(As, Ws, acc);
      __syncthreads();
    }
    store_tile_f16(acc, qk, 256, nullptr, nullptr, m0, n0, 0);
  }
}

// stage 7: gf/gs (A = EMA_inLDS(xp*wg)*cg + delta, sigmoid), soma (A = xh, tanh)
__global__ __launch_bounds__(256,3) void k_gemm_s7(
    const _Float16* __restrict__ xph, const _Float16* __restrict__ wgfs,
    const _Float16* __restrict__ xh, const _Float16* __restrict__ wall,
    const float* __restrict__ Hf, const float* __restrict__ Hs,
    const float* __restrict__ tau_fast, const float* __restrict__ tau_slow,
    const unsigned* __restrict__ cgE, const float* __restrict__ dlt,
    const float* __restrict__ bf, const float* __restrict__ bs, const float* __restrict__ bso,
    _Float16* __restrict__ gfb, _Float16* __restrict__ gsb, _Float16* __restrict__ somab)
{
  __shared__ _Float16 As[128*64];
  __shared__ _Float16 Wg[128*64];
  __shared__ _Float16 Bs[128*64];
  __shared__ float cgv[128];
  const size_t per = (size_t)C_*C_;
  floatx4 acc[4][4] = {};
  int m0 = blockIdx.x * 128;
  int s = blockIdx.y / 6, nt = (blockIdx.y % 6) * 128;
  int tid = threadIdx.x;
  if (s == 2){
    for (int k0 = 0; k0 < C_; k0 += 64){
      stage_tile(xh, C_, m0, k0, As);
      stage_tile(wall + 3*per, C_, nt, k0, Bs);   // Wsoma
      asm volatile("s_waitcnt vmcnt(0)" ::: "memory");
      __syncthreads();
      mfma_pass(As, Bs, acc);
      __syncthreads();
    }
    store_tile_f16(acc, somab, C_, bso, nullptr, m0, nt, 1);
  } else {
    float al = expf(-log1pf(expf(s ? tau_slow[0] : tau_fast[0])));
    const float* Hx = s ? Hs : Hf;
    const _Float16* wsrc = wgfs + (s ? C_ : 0);
    const _Float16* Wm = wall + (size_t)(s+1)*per;  // Wfast / Wslow
    int b = m0 >> 11;
    int ch0 = (m0 & (T_-1)) >> 3;
    if (tid < 128) cgv[tid] = sigm(dec_max(cgE[m0 + tid]));
    __syncthreads();
    int rc = tid >> 4, cc = (tid >> 1) & 7, hh = tid & 1;
    for (int k0 = 0; k0 < C_; k0 += 64){
      stage_tile(xph, C_, m0, k0, As);
      stage_tile(wsrc, K2_, m0, k0, Wg);
      stage_tile(Wm, C_, nt, k0, Bs);
      asm volatile("s_waitcnt vmcnt(0)" ::: "memory");
      __syncthreads();
      // in-place transform: As = EMA(xp*wg)*cg + delta (f16)
      {
        float4 hv = *(const float4*)(Hx + ((size_t)b*NCH_ + ch0 + rc)*C_ + k0 + cc*8 + hh*4);
        float4 d  = *(const float4*)(dlt + (size_t)b*C_ + k0 + cc*8 + hh*4);
        float e0=hv.x, e1=hv.y, e2=hv.z, e3=hv.w;
        #pragma unroll
        for (int r = 0; r < 8; ++r){
          int idx = (rc*8+r)*64 + ((cc^r)<<3) + hh*4;
          half4 p = *(const half4*)(As+idx);
          half4 wv = *(const half4*)(Wg+idx);
          e0 = al*e0 + (float)p[0]*(float)wv[0];
          e1 = al*e1 + (float)p[1]*(float)wv[1];
          e2 = al*e2 + (float)p[2]*(float)wv[2];
          e3 = al*e3 + (float)p[3]*(float)wv[3];
          float cgr = cgv[rc*8 + r];
          half4 o = { (_Float16)(e0*cgr + d.x), (_Float16)(e1*cgr + d.y),
                      (_Float16)(e2*cgr + d.z), (_Float16)(e3*cgr + d.w) };
          *(half4*)(As+idx) = o;
        }
      }
      __syncthreads();
      mfma_pass(As, Bs, acc);
      __syncthreads();
    }
    store_tile_f16(acc, s ? gsb : gfb, C_, s ? bs : bf, nullptr, m0, nt, 2);
  }
}

// ---------------- score (544 blocks) + fs_p1 (1024 blocks) in one launch, occ 3 ----------------
#define SLDK 104
__global__ __launch_bounds__(256,3) void k_score_fs(
    const _Float16* __restrict__ qk, unsigned* __restrict__ cgE,
    const _Float16* __restrict__ xp, const _Float16* __restrict__ wgfs,
    const float* __restrict__ tf, const float* __restrict__ ts,
    float* __restrict__ Sf, float* __restrict__ Ss)
{
  __shared__ _Float16 Qs[128*SLDK];
  __shared__ _Float16 Ks[128*SLDK];
  __shared__ float sred[256];
  int idx = blockIdx.x;
  int tid = threadIdx.x;
  if (idx >= 544){
    // ---- fs_p1 ----
    if (tid >= 192) return;
    int f = idx - 544;
    float af = expf(-log1pf(expf(tf[0])));
    float as = expf(-log1pf(expf(ts[0])));
    int b = f >> 8, ch = f & (NCH_-1);
    int t0 = b*T_ + ch*CK_;
    float f0=0,f1=0,f2=0,f3=0, s0=0,s1=0,s2=0,s3=0;
    #pragma unroll
    for (int t = 0; t < CK_; ++t){
      half4 p = *(const half4*)(xp + (size_t)(t0+t)*C_ + tid*4);
      half4 wf = *(const half4*)(wgfs + (size_t)(t0+t)*K2_ + tid*4);
      half4 ws = *(const half4*)(wgfs + (size_t)(t0+t)*K2_ + C_ + tid*4);
      f0 = af*f0 + (float)p[0]*(float)wf[0]; s0 = as*s0 + (float)p[0]*(float)ws[0];
      f1 = af*f1 + (float)p[1]*(float)wf[1]; s1 = as*s1 + (float)p[1]*(float)ws[1];
      f2 = af*f2 + (float)p[2]*(float)wf[2]; s2 = as*s2 + (float)p[2]*(float)ws[2];
      f3 = af*f3 + (float)p[3]*(float)wf[3]; s3 = as*s3 + (float)p[3]*(float)ws[3];
    }
    float4 fv = { f0,f1,f2,f3 }, sv = { s0,s1,s2,s3 };
    *(float4*)(Sf + (size_t)f*C_ + tid*4) = fv;
    *(float4*)(Ss + (size_t)f*C_ + tid*4) = sv;
    return;
  }
  // ---- score ----
  int b = idx / 136;
  int p = idx - b*136;
  int ti = (int)((sqrtf(8.f*p + 1.f) - 1.f)*0.5f);
  while ((ti+1)*(ti+2)/2 <= p) ++ti;
  while (ti*(ti+1)/2 > p) --ti;
  int sj = p - ti*(ti+1)/2;

  const _Float16* qg = qk + (size_t)(b*T_ + ti*128)*256;
  const _Float16* kg = qk + (size_t)(b*T_ + sj*128)*256 + 96;
  #pragma unroll
  for (int r = 0; r < 6; ++r){
    int ci = tid + r*256;
    int row = ci / 12, kp = ci % 12;
    *(uint4*)(&Qs[row*SLDK + kp*8]) = *(const uint4*)(qg + (size_t)row*256 + kp*8);
    *(uint4*)(&Ks[row*SLDK + kp*8]) = *(const uint4*)(kg + (size_t)row*256 + kp*8);
  }
  __syncthreads();

  int wave = tid >> 6, lane = tid & 63;
  int wr = wave >> 1, wc = wave & 1;
  int lr = lane & 15, lq = lane >> 4;
  floatx4 acc[4][4] = {};
  #pragma unroll
  for (int ks = 0; ks < 3; ++ks){
    half8 fa[4], fb[4];
    #pragma unroll
    for (int i = 0; i < 4; ++i){
      fa[i] = *(const half8*)(&Qs[(wr*64 + i*16 + lr)*SLDK + ks*32 + lq*8]);
      fb[i] = *(const half8*)(&Ks[(wc*64 + i*16 + lr)*SLDK + ks*32 + lq*8]);
    }
    #pragma unroll
    for (int i = 0; i < 4; ++i)
      #pragma unroll
      for (int j = 0; j < 4; ++j)
        acc[i][j] = __builtin_amdgcn_mfma_f32_16x16x32_f16(fa[i], fb[j], acc[i][j], 0, 0, 0);
  }
  const float scale = 0.10206207f;   // 96^-0.5
  #pragma unroll
  for (int i = 0; i < 4; ++i){
    #pragma unroll
    for (int r = 0; r < 4; ++r){
      int row64 = i*16 + lq*4 + r;
      int tg = ti*128 + wr*64 + row64;
      float v = -3.0e38f;
      #pragma unroll
      for (int j = 0; j < 4; ++j){
        int sg = sj*128 + wc*64 + j*16 + lr;
        if (sg <= tg) v = fmaxf(v, acc[i][j][r]*scale);
      }
      #pragma unroll
      for (int off = 1; off < 16; off <<= 1) v = fmaxf(v, __shfl_xor(v, off, 16));
      if (lr == 0) sred[wr*128 + wc*64 + row64] = v;
    }
  }
  __syncthreads();
  if (wc == 0 && lane < 64){
    int row64 = lane;
    float v = fmaxf(sred[wr*128 + row64], sred[wr*128 + 64 + row64]);
    int tg = ti*128 + wr*64 + row64;
    atomicMax(&cgE[(size_t)b*T_ + tg], enc_max(v));
  }
}

// ---------------- fused blend + soma-mul + LayerNorm: wave-per-row, no barriers ----------------
__global__ __launch_bounds__(256) void k_ln(const _Float16* __restrict__ gfb,
                                            const _Float16* __restrict__ gsb,
                                            const _Float16* __restrict__ somab,
                                            const float* __restrict__ blendr,
                                            const float* __restrict__ g, const float* __restrict__ be,
                                            float* __restrict__ out){
  int wave = threadIdx.x >> 6, lane = threadIdx.x & 63;
  int row = blockIdx.x*4 + wave;
  float bl = sigm(blendr[0]);
  size_t rb = (size_t)row*C_;
  float v[12];
  float s = 0.f, ss = 0.f;
  #pragma unroll
  for (int w2 = 0; w2 < 3; ++w2){
    size_t o = rb + w2*256 + lane*4;
    half4 gf4 = *(const half4*)(gfb + o);
    half4 gs4 = *(const half4*)(gsb + o);
    half4 so4 = *(const half4*)(somab + o);
    #pragma unroll
    for (int i = 0; i < 4; ++i){
      float gf = (float)gf4[i], gs = (float)gs4[i], so = (float)so4[i];
      float y = so * (gf + bl*(gs - gf));
      v[w2*4 + i] = y; s += y; ss += y*y;
    }
  }
  #pragma unroll
  for (int off = 1; off < 64; off <<= 1){ s += __shfl_xor(s, off); ss += __shfl_xor(ss, off); }
  float mu  = s * (1.f/C_);
  float var = ss * (1.f/C_) - mu*mu;
  float inv = rsqrtf(var + 1e-5f);
  #pragma unroll
  for (int w2 = 0; w2 < 3; ++w2){
    int c0 = w2*256 + lane*4;
    float4 o4;
    o4.x = (v[w2*4+0]-mu)*inv*g[c0+0] + be[c0+0];
    o4.y = (v[w2*4+1]-mu)*inv*g[c0+1] + be[c0+1];
    o4.z = (v[w2*4+2]-mu)*inv*g[c0+2] + be[c0+2];
    o4.w = (v[w2*4+3]-mu)*inv*g[c0+3] + be[c0+3];
    *(float4*)(out + rb + c0) = o4;
  }
}

// ---------------- launch ----------------
extern "C" void kernel_launch(void* const* d_in, const int* in_sizes, int n_in,
                              void* d_out, int out_size, void* d_ws, size_t ws_size,
                              hipStream_t stream){
  (void)in_sizes; (void)n_in; (void)out_size;
  const float* x        = (const float*)d_in[0];
  const float* tau_gate = (const float*)d_in[1];
  const float* tau_fast = (const float*)d_in[2];
  const float* tau_slow = (const float*)d_in[3];
  const float* Wp   = (const float*)d_in[4];  const float* bp    = (const float*)d_in[5];
  const float* Wxf  = (const float*)d_in[6];  const float* bxf   = (const float*)d_in[7];
  const float* Wxs  = (const float*)d_in[8];  const float* bxs   = (const float*)d_in[9];
  const float* Wcf  = (const float*)d_in[10]; const float* Wcs   = (const float*)d_in[11];
  const float* Wq   = (const float*)d_in[12]; const float* Wk    = (const float*)d_in[13];
  const float* Wfast= (const float*)d_in[14]; const float* bfast = (const float*)d_in[15];
  const float* Wslow= (const float*)d_in[16]; const float* bslow = (const float*)d_in[17];
  const float* Wsoma= (const float*)d_in[18]; const float* bsoma = (const float*)d_in[19];
  const float* Wanc = (const float*)d_in[20]; const float* banc  = (const float*)d_in[21];
  const float* ascl = (const float*)d_in[22]; const float* blendr= (const float*)d_in[23];
  const float* lng  = (const float*)d_in[24]; const float* lnb   = (const float*)d_in[25];
  float* out = (float*)d_out;

  char* w = (char*)d_ws;
  auto alloc = [&](size_t bytes)->void*{
    void* p = (void*)w; w += (bytes + 255) & ~(size_t)255; return p;
  };
  _Float16* xh    = (_Float16*)alloc((size_t)M_*C_*2);
  _Float16* wall  = (_Float16*)alloc((size_t)8*C_*C_*2);
  _Float16* wqk   = (_Float16*)alloc((size_t)256*C_*2);
  _Float16* xph   = (_Float16*)alloc((size_t)M_*C_*2);
  _Float16* wgfs  = (_Float16*)alloc((size_t)M_*K2_*2);
  _Float16* qk    = (_Float16*)alloc((size_t)M_*256*2);
  _Float16* gfb   = (_Float16*)alloc((size_t)M_*C_*2);
  _Float16* gsb   = (_Float16*)alloc((size_t)M_*C_*2);
  _Float16* somab = (_Float16*)alloc((size_t)M_*C_*2);
  unsigned* cgE   = (unsigned*)alloc((size_t)M_*4);
  float* Sg = (float*)alloc((size_t)B_*NCH_*C_*4);
  float* Hg = (float*)alloc((size_t)B_*NCH_*C_*4);
  float* Ss = (float*)alloc((size_t)B_*NCH_*C_*4);
  float* Hs = (float*)alloc((size_t)B_*NCH_*C_*4);
  float* dlt = (float*)alloc((size_t)B_*C_*4);
  // aliases (stream-ordered reuse):
  _Float16* gate = gfb;  // gate consumed by s3 (L4) before s7 (L7) writes gfb
  float* Sf = Sg;        // Sg consumed by prep's p2_gate (L2) before score_fs (L5) writes Sf
  float* Hf = Hg;        // Hg consumed by gate_p3 (L3) before p2_fs (L6) writes Hf
  if ((size_t)(w - (char*)d_ws) > ws_size) return;

  // L1: cast x -> xh + gate chunk sums
  k_castx<<<B_*NCH_, 192, 0, stream>>>(x, tau_gate, xh, Sg);
  // L2: weights, cgE, anchors, gate chunk-prefix (p2_gate hides under bulk casts)
  k_prep<<<NB3, 256, 0, stream>>>(x, Wp, Wfast, Wslow, Wsoma, Wxf, Wxs, Wcf, Wcs, Wq, Wk,
                                  Wanc, banc, ascl, tau_gate, Sg, wall, wqk, cgE, Hg, dlt);
  // L3: gate EMA stream -> gate buffer
  k_gate_p3<<<B_*NCH_, 192, 0, stream>>>(xh, Hg, tau_gate, gate);
  // L4: stage 3 (xp + wg split-K + q||k), clean 2-barrier K-loop
  k_gemm_s3<<<dim3(M_/128, 20), 256, 0, stream>>>(xh, gate, wall, wqk,
                                                  bp, bxf, bxs, xph, wgfs, qk);
  // L5: causal max score + fs chunk sums (independent, one launch, occ 3)
  k_score_fs<<<544 + B_*NCH_, 256, 0, stream>>>(qk, cgE, xph, wgfs, tau_fast, tau_slow, Sf, Ss);
  // L6: fast/slow chunk-prefix
  k_p2_fs<<<2*B_*3, 256, 0, stream>>>(Sf, Ss, Hf, Hs, tau_fast, tau_slow);
  // L7: stage 7 (gf/gs w/ in-LDS cf/cs derivation + soma)
  k_gemm_s7<<<dim3(M_/128, 18), 256, 0, stream>>>(xph, wgfs, xh, wall, Hf, Hs,
                                                  tau_fast, tau_slow, cgE, dlt,
                                                  bfast, bslow, bsoma, gfb, gsb, somab);
  // L8: fused blend + mul + LN (wave-per-row, barrier-free)
  k_ln<<<M_/4, 256, 0, stream>>>(gfb, gsb, somab, blendr, lng, lnb, out);
}